// Round 6
// baseline (694.294 us; speedup 1.0000x reference)
//
#include <hip/hip_runtime.h>
#include <math.h>

// Problem constants
#define TN 4096        // sequence length N
#define DM 512         // model dim D = H*DH
#define NH 8           // heads
#define DHD 64         // head dim
#define MEM 4          // memory slots M
#define WINR 512       // window radius
#define JTOT (TN + MEM)   // 4100 total keys
#define JPAD 4168      // padded key rows so tile over-reads stay in-bounds
#define QK_SCALE 10.0f

typedef __attribute__((ext_vector_type(8))) short bf16x8;   // 8 bf16 = 4 VGPRs (MFMA A/B frag)
typedef __attribute__((ext_vector_type(4))) float f32x4;    // MFMA C/D frag

// fp32 -> bf16 round-to-nearest-even
__device__ __forceinline__ unsigned short f2bf(float f) {
    unsigned u = __float_as_uint(f);
    u = (u + 0x7FFFu + ((u >> 16) & 1u)) >> 16;
    return (unsigned short)u;
}

// ---------------------------------------------------------------------------
// Cast X (fp32 [4096][512]) -> Xb (bf16). 512 blocks x 256 thr x 4 elems.
// ---------------------------------------------------------------------------
__global__ __launch_bounds__(256)
void cast_x(const float* __restrict__ X, unsigned short* __restrict__ Xb)
{
    int idx = blockIdx.x * blockDim.x + threadIdx.x;   // 0 .. 524287
    float4 v = *(const float4*)&X[(size_t)idx * 4];
    *(ushort4*)&Xb[(size_t)idx * 4] =
        make_ushort4(f2bf(v.x), f2bf(v.y), f2bf(v.z), f2bf(v.w));
}

// ---------------------------------------------------------------------------
// Transpose + cast weights: Wt[n][k] = bf16(W[k][n]), 512x512, z selects matrix.
// 64x64 tiles through LDS.
// ---------------------------------------------------------------------------
__global__ __launch_bounds__(256)
void transpose_cast(const float* __restrict__ W0, const float* __restrict__ W1,
                    const float* __restrict__ W2, const float* __restrict__ W3,
                    const float* __restrict__ W4, unsigned short* __restrict__ T)
{
    __shared__ unsigned short Ts[64][68];
    const int sel = blockIdx.z;
    const float* __restrict__ W =
        (sel == 0) ? W0 : (sel == 1) ? W1 : (sel == 2) ? W2 : (sel == 3) ? W3 : W4;
    unsigned short* __restrict__ Wt = T + (size_t)sel * DM * DM;
    const int r0 = blockIdx.x * 64;   // input row block (k)
    const int c0 = blockIdx.y * 64;   // input col block (n)
    const int t = threadIdx.x;

    #pragma unroll
    for (int p = 0; p < 4; ++p) {
        int i  = p * 16 + (t >> 4);
        int j4 = (t & 15) * 4;
        float4 v = *(const float4*)&W[(size_t)(r0 + i) * DM + c0 + j4];
        Ts[i][j4 + 0] = f2bf(v.x); Ts[i][j4 + 1] = f2bf(v.y);
        Ts[i][j4 + 2] = f2bf(v.z); Ts[i][j4 + 3] = f2bf(v.w);
    }
    __syncthreads();
    #pragma unroll
    for (int p = 0; p < 4; ++p) {
        int oc  = p * 16 + (t >> 4);   // output row = input col
        int or4 = (t & 15) * 4;        // output col chunk = input rows
        *(ushort4*)&Wt[(size_t)(c0 + oc) * DM + r0 + or4] =
            make_ushort4(Ts[or4 + 0][oc], Ts[or4 + 1][oc],
                         Ts[or4 + 2][oc], Ts[or4 + 3][oc]);
    }
}

// ---------------------------------------------------------------------------
// bf16 MFMA GEMM for Q/K/V/G projections. C = Xb @ W  via  Xb and Wt (= W^T).
// 128x128 tile, 256 thr = 4 waves, each wave 64x64 = 4x4 mfma_f32_16x16x32_bf16.
// A-frag: row = l&15, k = (l>>4)*8 + i  (row-major LDS [128][32] bf16).
// B-frag: col = l&15, k = (l>>4)*8 + i  (from Wt, same layout).
// C/D frag (verified m89): col = l&15, row = (l>>4)*4 + reg.
// ---------------------------------------------------------------------------
__global__ __launch_bounds__(256)
void gemm_qkvg_mfma(const unsigned short* __restrict__ Xb,
                    const unsigned short* __restrict__ Wt,  // 4 matrices back-to-back
                    float* __restrict__ q_ws, float* __restrict__ k_ws,
                    float* __restrict__ v_ws, float* __restrict__ graw)
{
    __shared__ __align__(16) unsigned short As[128][32];
    __shared__ __align__(16) unsigned short Bs[128][32];
    const int sel = blockIdx.z;
    const unsigned short* __restrict__ Wsel = Wt + (size_t)sel * DM * DM;
    const int row0 = blockIdx.x * 128;
    const int col0 = blockIdx.y * 128;
    const int t = threadIdx.x;
    const int w = t >> 6, l = t & 63;
    const int wm = w >> 1, wn = w & 1;           // wave -> 64x64 quadrant

    f32x4 acc[4][4];
    #pragma unroll
    for (int mi = 0; mi < 4; ++mi)
        #pragma unroll
        for (int ni = 0; ni < 4; ++ni)
            acc[mi][ni] = (f32x4){0.f, 0.f, 0.f, 0.f};

    for (int k0 = 0; k0 < DM; k0 += 32) {
        __syncthreads();   // protect LDS from previous iteration's readers
        #pragma unroll
        for (int cc = 0; cc < 2; ++cc) {
            int c = t + cc * 256;          // 0..511
            int row = c >> 2, k8 = c & 3;  // 128 rows x 4 k-chunks of 8
            *(bf16x8*)&As[row][k8 * 8] =
                *(const bf16x8*)&Xb[(size_t)(row0 + row) * DM + k0 + k8 * 8];
            *(bf16x8*)&Bs[row][k8 * 8] =
                *(const bf16x8*)&Wsel[(size_t)(col0 + row) * DM + k0 + k8 * 8];
        }
        __syncthreads();

        bf16x8 af[4], bfr[4];
        #pragma unroll
        for (int mi = 0; mi < 4; ++mi)
            af[mi] = *(const bf16x8*)&As[wm * 64 + mi * 16 + (l & 15)][(l >> 4) * 8];
        #pragma unroll
        for (int ni = 0; ni < 4; ++ni)
            bfr[ni] = *(const bf16x8*)&Bs[wn * 64 + ni * 16 + (l & 15)][(l >> 4) * 8];
        #pragma unroll
        for (int mi = 0; mi < 4; ++mi)
            #pragma unroll
            for (int ni = 0; ni < 4; ++ni)
                acc[mi][ni] = __builtin_amdgcn_mfma_f32_16x16x32_bf16(
                    af[mi], bfr[ni], acc[mi][ni], 0, 0, 0);
    }

    // epilogue: scatter to head-major q/k/v or row-major graw (fp32)
    #pragma unroll
    for (int mi = 0; mi < 4; ++mi) {
        #pragma unroll
        for (int ni = 0; ni < 4; ++ni) {
            int gcol = col0 + wn * 64 + ni * 16 + (l & 15);
            int h = gcol >> 6, d = gcol & 63;
            #pragma unroll
            for (int r = 0; r < 4; ++r) {
                int grow = row0 + wm * 64 + mi * 16 + (l >> 4) * 4 + r;
                float v = acc[mi][ni][r];
                if (sel == 3)      graw[(size_t)grow * DM + gcol] = v;
                else if (sel == 0) q_ws[(((size_t)h * TN + grow) << 6) + d] = v;
                else if (sel == 1) k_ws[(((size_t)h * JPAD + MEM + grow) << 6) + d] = v;
                else               v_ws[(((size_t)h * JPAD + MEM + grow) << 6) + d] = v;
            }
        }
    }
}

// ---------------------------------------------------------------------------
// bf16 MFMA GEMM: d_out = attnb @ Wo  via attnb (bf16) and Wo^T (bf16).
// ---------------------------------------------------------------------------
__global__ __launch_bounds__(256)
void gemm_out_mfma(const unsigned short* __restrict__ Ab,
                   const unsigned short* __restrict__ Wot,
                   float* __restrict__ C)
{
    __shared__ __align__(16) unsigned short As[128][32];
    __shared__ __align__(16) unsigned short Bs[128][32];
    const int row0 = blockIdx.x * 128;
    const int col0 = blockIdx.y * 128;
    const int t = threadIdx.x;
    const int w = t >> 6, l = t & 63;
    const int wm = w >> 1, wn = w & 1;

    f32x4 acc[4][4];
    #pragma unroll
    for (int mi = 0; mi < 4; ++mi)
        #pragma unroll
        for (int ni = 0; ni < 4; ++ni)
            acc[mi][ni] = (f32x4){0.f, 0.f, 0.f, 0.f};

    for (int k0 = 0; k0 < DM; k0 += 32) {
        __syncthreads();
        #pragma unroll
        for (int cc = 0; cc < 2; ++cc) {
            int c = t + cc * 256;
            int row = c >> 2, k8 = c & 3;
            *(bf16x8*)&As[row][k8 * 8] =
                *(const bf16x8*)&Ab[(size_t)(row0 + row) * DM + k0 + k8 * 8];
            *(bf16x8*)&Bs[row][k8 * 8] =
                *(const bf16x8*)&Wot[(size_t)(col0 + row) * DM + k0 + k8 * 8];
        }
        __syncthreads();

        bf16x8 af[4], bfr[4];
        #pragma unroll
        for (int mi = 0; mi < 4; ++mi)
            af[mi] = *(const bf16x8*)&As[wm * 64 + mi * 16 + (l & 15)][(l >> 4) * 8];
        #pragma unroll
        for (int ni = 0; ni < 4; ++ni)
            bfr[ni] = *(const bf16x8*)&Bs[wn * 64 + ni * 16 + (l & 15)][(l >> 4) * 8];
        #pragma unroll
        for (int mi = 0; mi < 4; ++mi)
            #pragma unroll
            for (int ni = 0; ni < 4; ++ni)
                acc[mi][ni] = __builtin_amdgcn_mfma_f32_16x16x32_bf16(
                    af[mi], bfr[ni], acc[mi][ni], 0, 0, 0);
    }

    #pragma unroll
    for (int mi = 0; mi < 4; ++mi)
        #pragma unroll
        for (int ni = 0; ni < 4; ++ni) {
            int gcol = col0 + wn * 64 + ni * 16 + (l & 15);
            #pragma unroll
            for (int r = 0; r < 4; ++r) {
                int grow = row0 + wm * 64 + mi * 16 + (l >> 4) * 4 + r;
                C[(size_t)grow * DM + gcol] = acc[mi][ni][r];
            }
        }
}

// ---------------------------------------------------------------------------
// Per-(head, n) wave: l2norm q,k; RoPE; sigmoid gate in-place. lane = head dim.
// (unchanged fp32 path)
// ---------------------------------------------------------------------------
__global__ __launch_bounds__(256)
void qk_norm_rope(float* __restrict__ q_ws, float* __restrict__ k_ws,
                  float* __restrict__ graw, const float* __restrict__ freqs,
                  const float* __restrict__ bg)
{
    int gw   = (blockIdx.x * blockDim.x + threadIdx.x) >> 6;  // 0..32767
    int lane = threadIdx.x & 63;
    int h = gw >> 12;
    int n = gw & 4095;

    float* qp = &q_ws[(((size_t)h * TN + n) << 6) + lane];
    float* kp = &k_ws[(((size_t)h * JPAD + MEM + n) << 6) + lane];
    float qv = *qp;
    float kv = *kp;

    float sq = qv * qv;
    float sk = kv * kv;
    #pragma unroll
    for (int off = 1; off < 64; off <<= 1) {
        sq += __shfl_xor(sq, off);
        sk += __shfl_xor(sk, off);
    }
    qv = qv / fmaxf(sqrtf(sq), 1e-12f);
    kv = kv / fmaxf(sqrtf(sk), 1e-12f);

    float f = freqs[(size_t)n * DHD + lane];
    float sn, cs;
    sincosf(f, &sn, &cs);
    float qo = __shfl_xor(qv, 32); qo = (lane < 32) ? -qo : qo;
    float ko = __shfl_xor(kv, 32); ko = (lane < 32) ? -ko : ko;
    *qp = qv * cs + qo * sn;
    *kp = kv * cs + ko * sn;

    size_t gi = (size_t)n * DM + h * DHD + lane;
    float g = graw[gi] + bg[h * DHD + lane];
    graw[gi] = 1.0f / (1.0f + __expf(-g));
}

// Memory KV rows: k_ws[h][0..3] = l2norm(mem_k), v_ws[h][0..3] = mem_v
__global__ void mem_init(const float* __restrict__ mem_k,
                         const float* __restrict__ mem_v,
                         float* __restrict__ k_ws, float* __restrict__ v_ws)
{
    int gw   = (blockIdx.x * blockDim.x + threadIdx.x) >> 6;
    int lane = threadIdx.x & 63;
    if (gw >= NH * MEM) return;
    int h = gw >> 2, m = gw & 3;
    float kv = mem_k[(size_t)(h * MEM + m) * DHD + lane];
    float s = kv * kv;
    #pragma unroll
    for (int off = 1; off < 64; off <<= 1) s += __shfl_xor(s, off);
    kv = kv / fmaxf(sqrtf(s), 1e-12f);
    k_ws[(((size_t)h * JPAD + m) << 6) + lane] = kv;
    v_ws[(((size_t)h * JPAD + m) << 6) + lane] = mem_v[(size_t)(h * MEM + m) * DHD + lane];
}

// ---------------------------------------------------------------------------
// Flash-style local attention (fp32, unchanged logic). Output bf16 attnb.
// ---------------------------------------------------------------------------
__global__ __launch_bounds__(256)
void attn_kernel(const float* __restrict__ q_ws, const float* __restrict__ k_ws,
                 const float* __restrict__ v_ws, const float* __restrict__ gate,
                 unsigned short* __restrict__ attnb)
{
    __shared__ float Qs[64][68];  // [d][n]  (transposed)
    __shared__ float Ks[64][68];  // [d][j]  (transposed)
    __shared__ float Vs[64][68];  // [j][d]
    __shared__ float Ps[64][68];  // [n][j]

    const int head = blockIdx.y;
    const int n0   = blockIdx.x * 64;
    const int t  = threadIdx.x;
    const int tx = t & 15;
    const int ty = t >> 4;

    {
        int nn = t >> 4;
        int d  = (t & 15) * 4;
        #pragma unroll
        for (int p = 0; p < 4; ++p) {
            int n = p * 16 + nn;
            float4 qv = *(const float4*)&q_ws[(((size_t)head * TN + n0 + n) << 6) + d];
            Qs[d + 0][n] = qv.x; Qs[d + 1][n] = qv.y;
            Qs[d + 2][n] = qv.z; Qs[d + 3][n] = qv.w;
        }
    }

    float O[4][4] = {};
    float mrow[4] = {-3.0e38f, -3.0e38f, -3.0e38f, -3.0e38f};
    float lrow[4] = {};

    const int p_base = MEM + n0;
    const int kstart = max(0, p_base - WINR);
    const int kend   = min(JTOT, p_base + 63 + WINR + 1);

    for (int j0 = kstart; j0 < kend; j0 += 64) {
        __syncthreads();
        {
            int jj = t >> 4;
            int d  = (t & 15) * 4;
            #pragma unroll
            for (int p = 0; p < 4; ++p) {
                int j = p * 16 + jj;
                size_t idx = (((size_t)head * JPAD + j0 + j) << 6) + d;
                float4 kq = *(const float4*)&k_ws[idx];
                Ks[d + 0][j] = kq.x; Ks[d + 1][j] = kq.y;
                Ks[d + 2][j] = kq.z; Ks[d + 3][j] = kq.w;
                *(float4*)&Vs[j][d] = *(const float4*)&v_ws[idx];
            }
        }
        __syncthreads();

        float s[4][4] = {};
        #pragma unroll
        for (int d = 0; d < 64; ++d) {
            float4 a = *(float4*)&Qs[d][ty * 4];
            float4 b = *(float4*)&Ks[d][tx * 4];
            float av[4] = {a.x, a.y, a.z, a.w};
            float bv[4] = {b.x, b.y, b.z, b.w};
            #pragma unroll
            for (int r = 0; r < 4; ++r)
                #pragma unroll
                for (int c = 0; c < 4; ++c)
                    s[r][c] += av[r] * bv[c];
        }

        #pragma unroll
        for (int r = 0; r < 4; ++r) {
            int pq = p_base + ty * 4 + r;
            float tm = -3.0e38f;
            #pragma unroll
            for (int c = 0; c < 4; ++c) {
                int j = j0 + tx * 4 + c;
                int dist = pq - j;
                bool ok = (dist <= WINR) && (dist >= -WINR) && (j < JTOT);
                float val = ok ? s[r][c] * QK_SCALE : -3.0e38f;
                s[r][c] = val;
                tm = fmaxf(tm, val);
            }
            #pragma unroll
            for (int off = 1; off < 16; off <<= 1) tm = fmaxf(tm, __shfl_xor(tm, off));
            float mnew = fmaxf(mrow[r], tm);
            float corr = __expf(mrow[r] - mnew);
            float pe[4];
            float rs = 0.0f;
            #pragma unroll
            for (int c = 0; c < 4; ++c) {
                pe[c] = (s[r][c] > -1.0e37f) ? __expf(s[r][c] - mnew) : 0.0f;
                rs += pe[c];
            }
            #pragma unroll
            for (int off = 1; off < 16; off <<= 1) rs += __shfl_xor(rs, off);
            lrow[r] = lrow[r] * corr + rs;
            mrow[r] = mnew;
            #pragma unroll
            for (int c = 0; c < 4; ++c) O[r][c] *= corr;
            *(float4*)&Ps[ty * 4 + r][tx * 4] = make_float4(pe[0], pe[1], pe[2], pe[3]);
        }
        __syncthreads();

        #pragma unroll
        for (int j = 0; j < 64; ++j) {
            float4 vb = *(float4*)&Vs[j][tx * 4];
            float vv[4] = {vb.x, vb.y, vb.z, vb.w};
            float p0 = Ps[ty * 4 + 0][j];
            float p1 = Ps[ty * 4 + 1][j];
            float p2 = Ps[ty * 4 + 2][j];
            float p3 = Ps[ty * 4 + 3][j];
            #pragma unroll
            for (int c = 0; c < 4; ++c) {
                O[0][c] += p0 * vv[c];
                O[1][c] += p1 * vv[c];
                O[2][c] += p2 * vv[c];
                O[3][c] += p3 * vv[c];
            }
        }
    }

    // epilogue: normalize, gate, write merged-head layout as bf16
    #pragma unroll
    for (int r = 0; r < 4; ++r) {
        int n   = n0 + ty * 4 + r;
        int col = head * 64 + tx * 4;
        float inv = 1.0f / lrow[r];
        float4 g = *(const float4*)&gate[(size_t)n * DM + col];
        *(ushort4*)&attnb[(size_t)n * DM + col] =
            make_ushort4(f2bf(O[r][0] * inv * g.x), f2bf(O[r][1] * inv * g.y),
                         f2bf(O[r][2] * inv * g.z), f2bf(O[r][3] * inv * g.w));
    }
}

// ---------------------------------------------------------------------------
extern "C" void kernel_launch(void* const* d_in, const int* in_sizes, int n_in,
                              void* d_out, int out_size, void* d_ws, size_t ws_size,
                              hipStream_t stream)
{
    const float* x     = (const float*)d_in[0];
    const float* Wq    = (const float*)d_in[1];
    const float* Wk    = (const float*)d_in[2];
    const float* Wv    = (const float*)d_in[3];
    const float* Wg    = (const float*)d_in[4];
    const float* bg    = (const float*)d_in[5];
    const float* Wo    = (const float*)d_in[6];
    const float* mem_k = (const float*)d_in[7];
    const float* mem_v = (const float*)d_in[8];
    const float* freqs = (const float*)d_in[9];

    // Workspace layout (≈38.7 MB total; attnb ALIASES Xb — Xb is dead after
    // gemm_qkvg_mfma, attnb is first written by attn_kernel; no overlap in DAG).
    float* ws    = (float*)d_ws;
    float* q_ws  = ws;                                    // [H][N][64] fp32      8.00 MB
    float* k_ws  = q_ws + (size_t)NH * TN * DHD;          // [H][JPAD][64] fp32   8.14 MB
    float* v_ws  = k_ws + (size_t)NH * JPAD * DHD;        // [H][JPAD][64] fp32   8.14 MB
    float* graw  = v_ws + (size_t)NH * JPAD * DHD;        // [N][512] fp32 gate   8.00 MB
    unsigned short* Xb    = (unsigned short*)(graw + (size_t)TN * DM); // bf16    4.00 MB
    unsigned short* attnb = Xb;                                        // (alias)
    unsigned short* Wt    = Xb + (size_t)TN * DM;  // 5x [512][512] bf16: q,k,v,g,o  2.62 MB

    // 0) cast X to bf16
    cast_x<<<dim3(TN * DM / 4 / 256), 256, 0, stream>>>(x, Xb);

    // 0b) transpose+cast the 5 weight matrices (z order: q,k,v,g,o)
    transpose_cast<<<dim3(8, 8, 5), 256, 0, stream>>>(Wq, Wk, Wv, Wg, Wo, Wt);

    // 1) fused Q/K/V/G projections via bf16 MFMA (z selects weight)
    gemm_qkvg_mfma<<<dim3(TN / 128, DM / 128, 4), 256, 0, stream>>>(
        Xb, Wt, q_ws, k_ws, v_ws, graw);

    // 2) l2norm + RoPE + sigmoid gate
    qk_norm_rope<<<dim3(NH * TN / 4), 256, 0, stream>>>(q_ws, k_ws, graw, freqs, bg);

    // 3) memory KV rows
    mem_init<<<dim3(8), 256, 0, stream>>>(mem_k, mem_v, k_ws, v_ws);

    // 4) local-window attention with gating (fp32 math, bf16 output; reuses Xb space)
    attn_kernel<<<dim3(TN / 64, NH), 256, 0, stream>>>(q_ws, k_ws, v_ws, graw, attnb);

    // 5) output projection via bf16 MFMA (Wo^T is 5th transposed matrix)
    gemm_out_mfma<<<dim3(TN / 128, DM / 128), 256, 0, stream>>>(
        attnb, Wt + (size_t)4 * DM * DM, (float*)d_out);
}

// Round 7
// 176.837 us; speedup vs baseline: 3.9262x; 3.9262x over previous
//
#include <hip/hip_runtime.h>
#include <math.h>

// Problem constants
#define TN 4096        // sequence length N
#define DM 512         // model dim D = H*DH
#define NH 8           // heads
#define DHD 64         // head dim
#define MEM 4          // memory slots M
#define WINR 512       // window radius
#define JTOT (TN + MEM)   // 4100 total keys
#define JPAD 4168      // padded key rows so tile over-reads stay in-bounds
#define QK_SCALE 10.0f

typedef __attribute__((ext_vector_type(8))) short bf16x8;   // 8 bf16 = 4 VGPRs (MFMA A/B frag)
typedef __attribute__((ext_vector_type(4))) float f32x4;    // MFMA C/D frag

// fp32 -> bf16 round-to-nearest-even
__device__ __forceinline__ unsigned short f2bf(float f) {
    unsigned u = __float_as_uint(f);
    u = (u + 0x7FFFu + ((u >> 16) & 1u)) >> 16;
    return (unsigned short)u;
}

// ---------------------------------------------------------------------------
// Cast X (fp32 [4096][512]) -> Xb (bf16).
// ---------------------------------------------------------------------------
__global__ __launch_bounds__(256)
void cast_x(const float* __restrict__ X, unsigned short* __restrict__ Xb)
{
    int idx = blockIdx.x * blockDim.x + threadIdx.x;   // 0 .. 524287
    float4 v = *(const float4*)&X[(size_t)idx * 4];
    *(ushort4*)&Xb[(size_t)idx * 4] =
        make_ushort4(f2bf(v.x), f2bf(v.y), f2bf(v.z), f2bf(v.w));
}

// ---------------------------------------------------------------------------
// Transpose + cast weights: Wt[n][k] = bf16(W[k][n]), 512x512, z selects matrix.
// ---------------------------------------------------------------------------
__global__ __launch_bounds__(256)
void transpose_cast(const float* __restrict__ W0, const float* __restrict__ W1,
                    const float* __restrict__ W2, const float* __restrict__ W3,
                    const float* __restrict__ W4, unsigned short* __restrict__ T)
{
    __shared__ unsigned short Ts[64][68];
    const int sel = blockIdx.z;
    const float* __restrict__ W =
        (sel == 0) ? W0 : (sel == 1) ? W1 : (sel == 2) ? W2 : (sel == 3) ? W3 : W4;
    unsigned short* __restrict__ Wt = T + (size_t)sel * DM * DM;
    const int r0 = blockIdx.x * 64;   // input row block (k)
    const int c0 = blockIdx.y * 64;   // input col block (n)
    const int t = threadIdx.x;

    #pragma unroll
    for (int p = 0; p < 4; ++p) {
        int i  = p * 16 + (t >> 4);
        int j4 = (t & 15) * 4;
        float4 v = *(const float4*)&W[(size_t)(r0 + i) * DM + c0 + j4];
        Ts[i][j4 + 0] = f2bf(v.x); Ts[i][j4 + 1] = f2bf(v.y);
        Ts[i][j4 + 2] = f2bf(v.z); Ts[i][j4 + 3] = f2bf(v.w);
    }
    __syncthreads();
    #pragma unroll
    for (int p = 0; p < 4; ++p) {
        int oc  = p * 16 + (t >> 4);   // output row = input col
        int or4 = (t & 15) * 4;        // output col chunk = input rows
        *(ushort4*)&Wt[(size_t)(c0 + oc) * DM + r0 + or4] =
            make_ushort4(Ts[or4 + 0][oc], Ts[or4 + 1][oc],
                         Ts[or4 + 2][oc], Ts[or4 + 3][oc]);
    }
}

// ---------------------------------------------------------------------------
// bf16 MFMA GEMM for Q/K/V/G projections. C = Xb @ W  via  Xb and Wt (= W^T).
// q/k fp32 head-major (normed later); v written DIRECTLY as bf16; g fp32.
// ---------------------------------------------------------------------------
__global__ __launch_bounds__(256)
void gemm_qkvg_mfma(const unsigned short* __restrict__ Xb,
                    const unsigned short* __restrict__ Wt,
                    float* __restrict__ q_ws, float* __restrict__ k_ws,
                    unsigned short* __restrict__ v_b, float* __restrict__ graw)
{
    __shared__ __align__(16) unsigned short As[128][32];
    __shared__ __align__(16) unsigned short Bs[128][32];
    const int sel = blockIdx.z;
    const unsigned short* __restrict__ Wsel = Wt + (size_t)sel * DM * DM;
    const int row0 = blockIdx.x * 128;
    const int col0 = blockIdx.y * 128;
    const int t = threadIdx.x;
    const int w = t >> 6, l = t & 63;
    const int wm = w >> 1, wn = w & 1;

    f32x4 acc[4][4];
    #pragma unroll
    for (int mi = 0; mi < 4; ++mi)
        #pragma unroll
        for (int ni = 0; ni < 4; ++ni)
            acc[mi][ni] = (f32x4){0.f, 0.f, 0.f, 0.f};

    for (int k0 = 0; k0 < DM; k0 += 32) {
        __syncthreads();
        #pragma unroll
        for (int cc = 0; cc < 2; ++cc) {
            int c = t + cc * 256;
            int row = c >> 2, k8 = c & 3;
            *(bf16x8*)&As[row][k8 * 8] =
                *(const bf16x8*)&Xb[(size_t)(row0 + row) * DM + k0 + k8 * 8];
            *(bf16x8*)&Bs[row][k8 * 8] =
                *(const bf16x8*)&Wsel[(size_t)(col0 + row) * DM + k0 + k8 * 8];
        }
        __syncthreads();

        bf16x8 af[4], bfr[4];
        #pragma unroll
        for (int mi = 0; mi < 4; ++mi)
            af[mi] = *(const bf16x8*)&As[wm * 64 + mi * 16 + (l & 15)][(l >> 4) * 8];
        #pragma unroll
        for (int ni = 0; ni < 4; ++ni)
            bfr[ni] = *(const bf16x8*)&Bs[wn * 64 + ni * 16 + (l & 15)][(l >> 4) * 8];
        #pragma unroll
        for (int mi = 0; mi < 4; ++mi)
            #pragma unroll
            for (int ni = 0; ni < 4; ++ni)
                acc[mi][ni] = __builtin_amdgcn_mfma_f32_16x16x32_bf16(
                    af[mi], bfr[ni], acc[mi][ni], 0, 0, 0);
    }

    #pragma unroll
    for (int mi = 0; mi < 4; ++mi) {
        #pragma unroll
        for (int ni = 0; ni < 4; ++ni) {
            int gcol = col0 + wn * 64 + ni * 16 + (l & 15);
            int h = gcol >> 6, d = gcol & 63;
            #pragma unroll
            for (int r = 0; r < 4; ++r) {
                int grow = row0 + wm * 64 + mi * 16 + (l >> 4) * 4 + r;
                float v = acc[mi][ni][r];
                if (sel == 3)      graw[(size_t)grow * DM + gcol] = v;
                else if (sel == 0) q_ws[(((size_t)h * TN + grow) << 6) + d] = v;
                else if (sel == 1) k_ws[(((size_t)h * JPAD + MEM + grow) << 6) + d] = v;
                else               v_b[((size_t)h * JPAD + MEM + grow) * 64 + d] = f2bf(v);
            }
        }
    }
}

// ---------------------------------------------------------------------------
// bf16 MFMA GEMM: d_out = attnb @ Wo.
// ---------------------------------------------------------------------------
__global__ __launch_bounds__(256)
void gemm_out_mfma(const unsigned short* __restrict__ Ab,
                   const unsigned short* __restrict__ Wot,
                   float* __restrict__ C)
{
    __shared__ __align__(16) unsigned short As[128][32];
    __shared__ __align__(16) unsigned short Bs[128][32];
    const int row0 = blockIdx.x * 128;
    const int col0 = blockIdx.y * 128;
    const int t = threadIdx.x;
    const int w = t >> 6, l = t & 63;
    const int wm = w >> 1, wn = w & 1;

    f32x4 acc[4][4];
    #pragma unroll
    for (int mi = 0; mi < 4; ++mi)
        #pragma unroll
        for (int ni = 0; ni < 4; ++ni)
            acc[mi][ni] = (f32x4){0.f, 0.f, 0.f, 0.f};

    for (int k0 = 0; k0 < DM; k0 += 32) {
        __syncthreads();
        #pragma unroll
        for (int cc = 0; cc < 2; ++cc) {
            int c = t + cc * 256;
            int row = c >> 2, k8 = c & 3;
            *(bf16x8*)&As[row][k8 * 8] =
                *(const bf16x8*)&Ab[(size_t)(row0 + row) * DM + k0 + k8 * 8];
            *(bf16x8*)&Bs[row][k8 * 8] =
                *(const bf16x8*)&Wot[(size_t)(col0 + row) * DM + k0 + k8 * 8];
        }
        __syncthreads();

        bf16x8 af[4], bfr[4];
        #pragma unroll
        for (int mi = 0; mi < 4; ++mi)
            af[mi] = *(const bf16x8*)&As[wm * 64 + mi * 16 + (l & 15)][(l >> 4) * 8];
        #pragma unroll
        for (int ni = 0; ni < 4; ++ni)
            bfr[ni] = *(const bf16x8*)&Bs[wn * 64 + ni * 16 + (l & 15)][(l >> 4) * 8];
        #pragma unroll
        for (int mi = 0; mi < 4; ++mi)
            #pragma unroll
            for (int ni = 0; ni < 4; ++ni)
                acc[mi][ni] = __builtin_amdgcn_mfma_f32_16x16x32_bf16(
                    af[mi], bfr[ni], acc[mi][ni], 0, 0, 0);
    }

    #pragma unroll
    for (int mi = 0; mi < 4; ++mi)
        #pragma unroll
        for (int ni = 0; ni < 4; ++ni) {
            int gcol = col0 + wn * 64 + ni * 16 + (l & 15);
            #pragma unroll
            for (int r = 0; r < 4; ++r) {
                int grow = row0 + wm * 64 + mi * 16 + (l >> 4) * 4 + r;
                C[(size_t)grow * DM + gcol] = acc[mi][ni][r];
            }
        }
}

// ---------------------------------------------------------------------------
// l2norm + RoPE in fp32, then write q/k as bf16 IN PLACE (first 128B of each
// 256B fp32 row). Also sigmoid gate in place (fp32).
// ---------------------------------------------------------------------------
__global__ __launch_bounds__(256)
void qk_norm_rope(float* __restrict__ q_ws, float* __restrict__ k_ws,
                  float* __restrict__ graw, const float* __restrict__ freqs,
                  const float* __restrict__ bg)
{
    int gw   = (blockIdx.x * blockDim.x + threadIdx.x) >> 6;  // 0..32767
    int lane = threadIdx.x & 63;
    int h = gw >> 12;
    int n = gw & 4095;

    float* qrow = &q_ws[((size_t)h * TN + n) << 6];
    float* krow = &k_ws[((size_t)h * JPAD + MEM + n) << 6];
    float qv = qrow[lane];
    float kv = krow[lane];

    float sq = qv * qv;
    float sk = kv * kv;
    #pragma unroll
    for (int off = 1; off < 64; off <<= 1) {
        sq += __shfl_xor(sq, off);
        sk += __shfl_xor(sk, off);
    }
    qv = qv / fmaxf(sqrtf(sq), 1e-12f);
    kv = kv / fmaxf(sqrtf(sk), 1e-12f);

    float f = freqs[(size_t)n * DHD + lane];
    float sn, cs;
    sincosf(f, &sn, &cs);
    float qo = __shfl_xor(qv, 32); qo = (lane < 32) ? -qo : qo;
    float ko = __shfl_xor(kv, 32); ko = (lane < 32) ? -ko : ko;
    float qr = qv * cs + qo * sn;
    float kr = kv * cs + ko * sn;

    // fence: the bf16 stores below alias the fp32 rows just read (type-punned)
    asm volatile("" ::: "memory");
    ((unsigned short*)qrow)[lane] = f2bf(qr);
    ((unsigned short*)krow)[lane] = f2bf(kr);

    size_t gi = (size_t)n * DM + h * DHD + lane;
    float g = graw[gi] + bg[h * DHD + lane];
    graw[gi] = 1.0f / (1.0f + __expf(-g));
}

// Memory KV rows 0..3: bf16 l2norm(mem_k) into k rows, bf16 mem_v into v_b.
__global__ void mem_init(const float* __restrict__ mem_k,
                         const float* __restrict__ mem_v,
                         float* __restrict__ k_ws, unsigned short* __restrict__ v_b)
{
    int gw   = (blockIdx.x * blockDim.x + threadIdx.x) >> 6;
    int lane = threadIdx.x & 63;
    if (gw >= NH * MEM) return;
    int h = gw >> 2, m = gw & 3;
    float kv = mem_k[(size_t)(h * MEM + m) * DHD + lane];
    float s = kv * kv;
    #pragma unroll
    for (int off = 1; off < 64; off <<= 1) s += __shfl_xor(s, off);
    kv = kv / fmaxf(sqrtf(s), 1e-12f);
    ((unsigned short*)k_ws)[(((size_t)h * JPAD + m) << 7) + lane] = f2bf(kv);
    v_b[((size_t)h * JPAD + m) * 64 + lane] = f2bf(mem_v[(size_t)(h * MEM + m) * DHD + lane]);
}

// ---------------------------------------------------------------------------
// MFMA flash attention. Block = (64 q-rows, head); 4 waves, one 16-row band
// each. bf16 16x16x32 MFMA for QK^T and PV; fp32 online softmax.
// LDS tiles padded to 72 ushorts/row (144B: 16B bank rotation, 2-way = free).
// ---------------------------------------------------------------------------
__global__ __launch_bounds__(256)
void attn_mfma(const unsigned short* __restrict__ qb,
               const unsigned short* __restrict__ kb,
               const unsigned short* __restrict__ vb,
               const float* __restrict__ gate,
               unsigned short* __restrict__ attnb)
{
    __shared__ __align__(16) unsigned short Qs[64][72];
    __shared__ __align__(16) unsigned short Ks[64][72];
    __shared__ __align__(16) unsigned short Vt[64][72];   // [d][k]
    __shared__ __align__(16) unsigned short Ps[64][72];

    // XCD swizzle: 512 blocks, blocks of one head land on one XCD (L2 reuse)
    const int sw   = (blockIdx.x & 7) * 64 + (blockIdx.x >> 3);
    const int head = sw >> 6;
    const int n0   = (sw & 63) * 64;
    const int t = threadIdx.x;
    const int wid = t >> 6;          // q-band
    const int l = t & 63;
    const int l15 = l & 15, lh = l >> 4;

    // stage Q once (row stride in qb = 128 ushorts; payload = first 64)
    #pragma unroll
    for (int it = 0; it < 2; ++it) {
        int idx = t + it * 256;
        int row = idx >> 3, c8 = (idx & 7) * 8;
        *(bf16x8*)&Qs[row][c8] =
            *(const bf16x8*)&qb[((size_t)(head * TN + n0 + row) << 7) + c8];
    }

    f32x4 oacc[4];
    #pragma unroll
    for (int dt = 0; dt < 4; ++dt) oacc[dt] = (f32x4){0.f, 0.f, 0.f, 0.f};
    float mrow[4] = {-3.0e38f, -3.0e38f, -3.0e38f, -3.0e38f};
    float lrow[4] = {0.f, 0.f, 0.f, 0.f};

    const int p_base = MEM + n0;
    const int kstart = max(0, p_base - WINR);
    const int kend   = min(JTOT, p_base + 63 + WINR + 1);

    for (int j0 = kstart; j0 < kend; j0 += 64) {
        __syncthreads();   // prior tile's consumers done before restaging
        // stage K (coalesced) and V transposed
        #pragma unroll
        for (int it = 0; it < 2; ++it) {
            int idx = t + it * 256;
            int row = idx >> 3, c8 = (idx & 7) * 8;
            *(bf16x8*)&Ks[row][c8] =
                *(const bf16x8*)&kb[((size_t)(head * JPAD + j0 + row) << 7) + c8];
            int j = idx & 63, d0 = (idx >> 6) * 8;
            bf16x8 vv = *(const bf16x8*)&vb[(size_t)(head * JPAD + j0 + j) * 64 + d0];
            #pragma unroll
            for (int i = 0; i < 8; ++i) Vt[d0 + i][j] = (unsigned short)vv[i];
        }
        __syncthreads();

        // S band = Q[band] @ K^T : 4 col-tiles x 2 k-steps
        f32x4 sacc[4];
        #pragma unroll
        for (int kt = 0; kt < 4; ++kt) sacc[kt] = (f32x4){0.f, 0.f, 0.f, 0.f};
        #pragma unroll
        for (int s = 0; s < 2; ++s) {
            bf16x8 a = *(const bf16x8*)&Qs[wid * 16 + l15][s * 32 + lh * 8];
            #pragma unroll
            for (int kt = 0; kt < 4; ++kt) {
                bf16x8 b = *(const bf16x8*)&Ks[kt * 16 + l15][s * 32 + lh * 8];
                sacc[kt] = __builtin_amdgcn_mfma_f32_16x16x32_bf16(a, b, sacc[kt], 0, 0, 0);
            }
        }

        // mask + online softmax (C/D: row q = lh*4+r, col k = kt*16+l15)
        #pragma unroll
        for (int r = 0; r < 4; ++r) {
            int pq = p_base + wid * 16 + lh * 4 + r;
            float sv[4];
            float tm = -3.0e38f;
            #pragma unroll
            for (int kt = 0; kt < 4; ++kt) {
                int j = j0 + kt * 16 + l15;
                int dist = pq - j;
                bool ok = (dist <= WINR) && (dist >= -WINR) && (j < JTOT);
                float val = ok ? sacc[kt][r] * QK_SCALE : -3.0e38f;
                sv[kt] = val;
                tm = fmaxf(tm, val);
            }
            #pragma unroll
            for (int off = 1; off < 16; off <<= 1) tm = fmaxf(tm, __shfl_xor(tm, off));
            float mnew = fmaxf(mrow[r], tm);
            float corr = __expf(mrow[r] - mnew);
            float rs = 0.f;
            #pragma unroll
            for (int kt = 0; kt < 4; ++kt) {
                float pe = (sv[kt] > -1.0e37f) ? __expf(sv[kt] - mnew) : 0.f;
                rs += pe;
                Ps[wid * 16 + lh * 4 + r][kt * 16 + l15] = f2bf(pe);
            }
            #pragma unroll
            for (int off = 1; off < 16; off <<= 1) rs += __shfl_xor(rs, off);
            lrow[r] = lrow[r] * corr + rs;
            mrow[r] = mnew;
            #pragma unroll
            for (int dt = 0; dt < 4; ++dt) oacc[dt][r] *= corr;
        }
        __syncthreads();

        // O += P @ V : A = Ps[band] (k-contig), B = Vt[d][k] (k-contig)
        #pragma unroll
        for (int s = 0; s < 2; ++s) {
            bf16x8 a = *(const bf16x8*)&Ps[wid * 16 + l15][s * 32 + lh * 8];
            #pragma unroll
            for (int dt = 0; dt < 4; ++dt) {
                bf16x8 b = *(const bf16x8*)&Vt[dt * 16 + l15][s * 32 + lh * 8];
                oacc[dt] = __builtin_amdgcn_mfma_f32_16x16x32_bf16(a, b, oacc[dt], 0, 0, 0);
            }
        }
    }

    // epilogue: normalize, gate, write merged-head bf16
    #pragma unroll
    for (int r = 0; r < 4; ++r) {
        int n = n0 + wid * 16 + lh * 4 + r;
        float inv = 1.0f / lrow[r];
        #pragma unroll
        for (int dt = 0; dt < 4; ++dt) {
            int col = head * 64 + dt * 16 + l15;
            float g = gate[(size_t)n * DM + col];
            attnb[(size_t)n * DM + col] = f2bf(oacc[dt][r] * inv * g);
        }
    }
}

// ---------------------------------------------------------------------------
extern "C" void kernel_launch(void* const* d_in, const int* in_sizes, int n_in,
                              void* d_out, int out_size, void* d_ws, size_t ws_size,
                              hipStream_t stream)
{
    const float* x     = (const float*)d_in[0];
    const float* Wq    = (const float*)d_in[1];
    const float* Wk    = (const float*)d_in[2];
    const float* Wv    = (const float*)d_in[3];
    const float* Wg    = (const float*)d_in[4];
    const float* bg    = (const float*)d_in[5];
    const float* Wo    = (const float*)d_in[6];
    const float* mem_k = (const float*)d_in[7];
    const float* mem_v = (const float*)d_in[8];
    const float* freqs = (const float*)d_in[9];

    // Workspace (~34.8 MB). q_ws/k_ws fp32 rows are rewritten in place as bf16
    // by qk_norm_rope (payload = first 128B of each 256B row). attnb aliases
    // Xb (Xb dead after gemm_qkvg_mfma; attnb first written by attn_mfma).
    float* q_ws = (float*)d_ws;                           // [H][N][64] fp32->bf16
    float* k_ws = q_ws + (size_t)NH * TN * DHD;           // [H][JPAD][64] fp32->bf16
    float* graw = k_ws + (size_t)NH * JPAD * DHD;         // [N][512] fp32 gate
    unsigned short* v_b   = (unsigned short*)(graw + (size_t)TN * DM); // [H][JPAD][64] bf16
    unsigned short* Xb    = v_b + (size_t)NH * JPAD * DHD;             // [N][512] bf16
    unsigned short* attnb = Xb;                                        // alias
    unsigned short* Wt    = Xb + (size_t)TN * DM;  // 5x [512][512] bf16: q,k,v,g,o

    // 0) cast X to bf16
    cast_x<<<dim3(TN * DM / 4 / 256), 256, 0, stream>>>(x, Xb);

    // 0b) transpose+cast the 5 weight matrices
    transpose_cast<<<dim3(8, 8, 5), 256, 0, stream>>>(Wq, Wk, Wv, Wg, Wo, Wt);

    // 1) Q/K/V/G projections (bf16 MFMA); V emitted directly as bf16
    gemm_qkvg_mfma<<<dim3(TN / 128, DM / 128, 4), 256, 0, stream>>>(
        Xb, Wt, q_ws, k_ws, v_b, graw);

    // 2) l2norm + RoPE (fp32) -> bf16 q/k in place; sigmoid gate
    qk_norm_rope<<<dim3(NH * TN / 4), 256, 0, stream>>>(q_ws, k_ws, graw, freqs, bg);

    // 3) memory KV rows (bf16)
    mem_init<<<dim3(8), 256, 0, stream>>>(mem_k, mem_v, k_ws, v_b);

    // 4) MFMA local-window attention with gating
    attn_mfma<<<dim3(512), 256, 0, stream>>>(
        (const unsigned short*)q_ws, (const unsigned short*)k_ws, v_b, graw, attnb);

    // 5) output projection (bf16 MFMA)
    gemm_out_mfma<<<dim3(TN / 128, DM / 128), 256, 0, stream>>>(
        attnb, Wt + (size_t)4 * DM * DM, (float*)d_out);
}

// Round 9
// 173.576 us; speedup vs baseline: 3.9999x; 1.0188x over previous
//
#include <hip/hip_runtime.h>
#include <math.h>

// Problem constants
#define TN 4096        // sequence length N
#define DM 512         // model dim D = H*DH
#define NH 8           // heads
#define DHD 64         // head dim
#define MEM 4          // memory slots M
#define WINR 512       // window radius
#define JTOT (TN + MEM)   // 4100 total keys
#define JPAD 4168      // padded key rows so tile over-reads stay in-bounds
#define QK_SCALE 10.0f

typedef __attribute__((ext_vector_type(8))) short bf16x8;   // 8 bf16 = 4 VGPRs (MFMA A/B frag)
typedef __attribute__((ext_vector_type(4))) float f32x4;    // MFMA C/D frag

// fp32 -> bf16 round-to-nearest-even
__device__ __forceinline__ unsigned short f2bf(float f) {
    unsigned u = __float_as_uint(f);
    u = (u + 0x7FFFu + ((u >> 16) & 1u)) >> 16;
    return (unsigned short)u;
}

// ---------------------------------------------------------------------------
// Sectioned prep kernel (one launch, 2440 blocks):
//   blocks    0..2047 : cast X fp32 -> bf16   (2048*256*4 = 2,097,152 = TN*DM)
//   blocks 2048..2367 : transpose+cast 5 weight matrices -> Wt (bf16, [n][k])
//   blocks 2368..2431 : rope table tab[n][d] = (cos,sin) fp32 (accurate sincosf)
//   blocks 2432..2439 : memory KV rows (l2norm mem_k, mem_v) as bf16
// No cross-section dependencies.
// (Round-8 bug: cast section had 512 blocks -> only 1/4 of X cast; rows >=1024
//  were 0xAA poison, l2norm blew unit-norm garbage k-rows -> absmax 5.8e-2.)
// ---------------------------------------------------------------------------
__global__ __launch_bounds__(256)
void prep(const float* __restrict__ X, unsigned short* __restrict__ Xb,
          const float* __restrict__ W0, const float* __restrict__ W1,
          const float* __restrict__ W2, const float* __restrict__ W3,
          const float* __restrict__ W4, unsigned short* __restrict__ T,
          const float* __restrict__ freqs, float2* __restrict__ tab,
          const float* __restrict__ mem_k, const float* __restrict__ mem_v,
          unsigned short* __restrict__ k_b, unsigned short* __restrict__ v_b)
{
    const int b = blockIdx.x;
    const int t = threadIdx.x;

    if (b < 2048) {                      // ---- cast X (full matrix)
        int idx = b * 256 + t;           // 0 .. 524287, 4 floats each
        float4 v = *(const float4*)&X[(size_t)idx * 4];
        *(ushort4*)&Xb[(size_t)idx * 4] =
            make_ushort4(f2bf(v.x), f2bf(v.y), f2bf(v.z), f2bf(v.w));
    } else if (b < 2368) {               // ---- weight transpose+cast
        __shared__ unsigned short Ts[64][68];
        int bi = b - 2048;
        int sel = bi >> 6, tile = bi & 63;
        const float* __restrict__ W =
            (sel == 0) ? W0 : (sel == 1) ? W1 : (sel == 2) ? W2 : (sel == 3) ? W3 : W4;
        unsigned short* __restrict__ Wt = T + (size_t)sel * DM * DM;
        int r0 = (tile >> 3) * 64, c0 = (tile & 7) * 64;
        #pragma unroll
        for (int p = 0; p < 4; ++p) {
            int i  = p * 16 + (t >> 4);
            int j4 = (t & 15) * 4;
            float4 v = *(const float4*)&W[(size_t)(r0 + i) * DM + c0 + j4];
            Ts[i][j4 + 0] = f2bf(v.x); Ts[i][j4 + 1] = f2bf(v.y);
            Ts[i][j4 + 2] = f2bf(v.z); Ts[i][j4 + 3] = f2bf(v.w);
        }
        __syncthreads();
        #pragma unroll
        for (int p = 0; p < 4; ++p) {
            int oc  = p * 16 + (t >> 4);
            int or4 = (t & 15) * 4;
            *(ushort4*)&Wt[(size_t)(c0 + oc) * DM + r0 + or4] =
                make_ushort4(Ts[or4 + 0][oc], Ts[or4 + 1][oc],
                             Ts[or4 + 2][oc], Ts[or4 + 3][oc]);
        }
    } else if (b < 2432) {               // ---- rope cos/sin table
        int tid = (b - 2368) * 256 + t;  // 0..16383
        #pragma unroll
        for (int e = 0; e < 16; ++e) {
            int id = e * 16384 + tid;    // 0..262143, coalesced
            float f = freqs[id];
            float sn, cs;
            sincosf(f, &sn, &cs);
            tab[id] = make_float2(cs, sn);
        }
    } else {                             // ---- memory KV rows
        int gw   = (b - 2432) * 4 + (t >> 6);   // 0..31
        int lane = t & 63;
        int h = gw >> 2, m = gw & 3;
        float kv = mem_k[(size_t)(h * MEM + m) * DHD + lane];
        float s = kv * kv;
        #pragma unroll
        for (int off = 1; off < 64; off <<= 1) s += __shfl_xor(s, off);
        kv = kv / fmaxf(sqrtf(s), 1e-12f);
        k_b[((size_t)h * JPAD + m) * 64 + lane] = f2bf(kv);
        v_b[((size_t)h * JPAD + m) * 64 + lane] =
            f2bf(mem_v[(size_t)(h * MEM + m) * DHD + lane]);
    }
}

// ---------------------------------------------------------------------------
// bf16 MFMA GEMM for Q/K/V/G projections with FUSED epilogue:
//   sel 0/1 (q/k): in-register l2norm (shfl over l15) + RoPE (table) -> bf16
//   sel 2   (v):   bf16 direct
//   sel 3   (g):   +bias, sigmoid -> fp32
// Each wave's 64-col span = exactly one head (col0 64-aligned), so the d=0..63
// norm reduction is wave-local: thread holds 4 cols (ni*16+l15), shfl_xor
// 1/2/4/8 sums over the 16 l15 lanes. RoPE pairs d and d+32 = ni and ni+2,
// both in-thread. Math identical to the round-7 separate-kernel pipeline.
// ---------------------------------------------------------------------------
__global__ __launch_bounds__(256)
void gemm_qkvg_mfma(const unsigned short* __restrict__ Xb,
                    const unsigned short* __restrict__ Wt,
                    const float2* __restrict__ tab,
                    const float* __restrict__ bg,
                    unsigned short* __restrict__ q_b,
                    unsigned short* __restrict__ k_b,
                    unsigned short* __restrict__ v_b,
                    float* __restrict__ graw)
{
    __shared__ __align__(16) unsigned short As[128][32];
    __shared__ __align__(16) unsigned short Bs[128][32];
    const int sel = blockIdx.z;
    const unsigned short* __restrict__ Wsel = Wt + (size_t)sel * DM * DM;
    const int row0 = blockIdx.x * 128;
    const int col0 = blockIdx.y * 128;
    const int t = threadIdx.x;
    const int w = t >> 6, l = t & 63;
    const int wm = w >> 1, wn = w & 1;
    const int l15 = l & 15, lh = l >> 4;

    f32x4 acc[4][4];
    #pragma unroll
    for (int mi = 0; mi < 4; ++mi)
        #pragma unroll
        for (int ni = 0; ni < 4; ++ni)
            acc[mi][ni] = (f32x4){0.f, 0.f, 0.f, 0.f};

    for (int k0 = 0; k0 < DM; k0 += 32) {
        __syncthreads();
        #pragma unroll
        for (int cc = 0; cc < 2; ++cc) {
            int c = t + cc * 256;
            int row = c >> 2, k8 = c & 3;
            *(bf16x8*)&As[row][k8 * 8] =
                *(const bf16x8*)&Xb[(size_t)(row0 + row) * DM + k0 + k8 * 8];
            *(bf16x8*)&Bs[row][k8 * 8] =
                *(const bf16x8*)&Wsel[(size_t)(col0 + row) * DM + k0 + k8 * 8];
        }
        __syncthreads();

        bf16x8 af[4], bfr[4];
        #pragma unroll
        for (int mi = 0; mi < 4; ++mi)
            af[mi] = *(const bf16x8*)&As[wm * 64 + mi * 16 + l15][lh * 8];
        #pragma unroll
        for (int ni = 0; ni < 4; ++ni)
            bfr[ni] = *(const bf16x8*)&Bs[wn * 64 + ni * 16 + l15][lh * 8];
        #pragma unroll
        for (int mi = 0; mi < 4; ++mi)
            #pragma unroll
            for (int ni = 0; ni < 4; ++ni)
                acc[mi][ni] = __builtin_amdgcn_mfma_f32_16x16x32_bf16(
                    af[mi], bfr[ni], acc[mi][ni], 0, 0, 0);
    }

    if (sel <= 1) {
        // q/k: l2norm + RoPE + bf16 store. Head h is wave-constant.
        const int h = (col0 + wn * 64) >> 6;
        #pragma unroll
        for (int mi = 0; mi < 4; ++mi) {
            #pragma unroll
            for (int r = 0; r < 4; ++r) {
                float v0 = acc[mi][0][r], v1 = acc[mi][1][r];
                float v2 = acc[mi][2][r], v3 = acc[mi][3][r];
                float ss = v0 * v0 + v1 * v1 + v2 * v2 + v3 * v3;
                ss += __shfl_xor(ss, 1); ss += __shfl_xor(ss, 2);
                ss += __shfl_xor(ss, 4); ss += __shfl_xor(ss, 8);
                float inv = 1.0f / fmaxf(sqrtf(ss), 1e-12f);
                v0 *= inv; v1 *= inv; v2 *= inv; v3 *= inv;
                int n = row0 + wm * 64 + mi * 16 + lh * 4 + r;
                float2 t0 = tab[n * 64 + l15];        // d = l15  (freqs[d]==freqs[d+32])
                float2 t1 = tab[n * 64 + 16 + l15];   // d = 16+l15
                float o0 = v0 * t0.x - v2 * t0.y;     // d < 32: rot = -q[d+32]
                float o1 = v1 * t1.x - v3 * t1.y;
                float o2 = v2 * t0.x + v0 * t0.y;     // d >= 32: rot = q[d-32]
                float o3 = v3 * t1.x + v1 * t1.y;
                unsigned short* dst = (sel == 0)
                    ? &q_b[((size_t)h * TN + n) * 64]
                    : &k_b[((size_t)h * JPAD + MEM + n) * 64];
                dst[l15]      = f2bf(o0);
                dst[16 + l15] = f2bf(o1);
                dst[32 + l15] = f2bf(o2);
                dst[48 + l15] = f2bf(o3);
            }
        }
    } else if (sel == 2) {
        const int h = (col0 + wn * 64) >> 6;
        #pragma unroll
        for (int mi = 0; mi < 4; ++mi)
            #pragma unroll
            for (int ni = 0; ni < 4; ++ni) {
                int d = ni * 16 + l15;
                #pragma unroll
                for (int r = 0; r < 4; ++r) {
                    int grow = row0 + wm * 64 + mi * 16 + lh * 4 + r;
                    v_b[((size_t)h * JPAD + MEM + grow) * 64 + d] = f2bf(acc[mi][ni][r]);
                }
            }
    } else {
        #pragma unroll
        for (int mi = 0; mi < 4; ++mi)
            #pragma unroll
            for (int ni = 0; ni < 4; ++ni) {
                int gcol = col0 + wn * 64 + ni * 16 + l15;
                float bgv = bg[gcol];
                #pragma unroll
                for (int r = 0; r < 4; ++r) {
                    int grow = row0 + wm * 64 + mi * 16 + lh * 4 + r;
                    float g = acc[mi][ni][r] + bgv;
                    graw[(size_t)grow * DM + gcol] = 1.0f / (1.0f + __expf(-g));
                }
            }
    }
}

// ---------------------------------------------------------------------------
// bf16 MFMA GEMM: d_out = attnb @ Wo.
// ---------------------------------------------------------------------------
__global__ __launch_bounds__(256)
void gemm_out_mfma(const unsigned short* __restrict__ Ab,
                   const unsigned short* __restrict__ Wot,
                   float* __restrict__ C)
{
    __shared__ __align__(16) unsigned short As[128][32];
    __shared__ __align__(16) unsigned short Bs[128][32];
    const int row0 = blockIdx.x * 128;
    const int col0 = blockIdx.y * 128;
    const int t = threadIdx.x;
    const int w = t >> 6, l = t & 63;
    const int wm = w >> 1, wn = w & 1;

    f32x4 acc[4][4];
    #pragma unroll
    for (int mi = 0; mi < 4; ++mi)
        #pragma unroll
        for (int ni = 0; ni < 4; ++ni)
            acc[mi][ni] = (f32x4){0.f, 0.f, 0.f, 0.f};

    for (int k0 = 0; k0 < DM; k0 += 32) {
        __syncthreads();
        #pragma unroll
        for (int cc = 0; cc < 2; ++cc) {
            int c = t + cc * 256;
            int row = c >> 2, k8 = c & 3;
            *(bf16x8*)&As[row][k8 * 8] =
                *(const bf16x8*)&Ab[(size_t)(row0 + row) * DM + k0 + k8 * 8];
            *(bf16x8*)&Bs[row][k8 * 8] =
                *(const bf16x8*)&Wot[(size_t)(col0 + row) * DM + k0 + k8 * 8];
        }
        __syncthreads();

        bf16x8 af[4], bfr[4];
        #pragma unroll
        for (int mi = 0; mi < 4; ++mi)
            af[mi] = *(const bf16x8*)&As[wm * 64 + mi * 16 + (l & 15)][(l >> 4) * 8];
        #pragma unroll
        for (int ni = 0; ni < 4; ++ni)
            bfr[ni] = *(const bf16x8*)&Bs[wn * 64 + ni * 16 + (l & 15)][(l >> 4) * 8];
        #pragma unroll
        for (int mi = 0; mi < 4; ++mi)
            #pragma unroll
            for (int ni = 0; ni < 4; ++ni)
                acc[mi][ni] = __builtin_amdgcn_mfma_f32_16x16x32_bf16(
                    af[mi], bfr[ni], acc[mi][ni], 0, 0, 0);
    }

    #pragma unroll
    for (int mi = 0; mi < 4; ++mi)
        #pragma unroll
        for (int ni = 0; ni < 4; ++ni) {
            int gcol = col0 + wn * 64 + ni * 16 + (l & 15);
            #pragma unroll
            for (int r = 0; r < 4; ++r) {
                int grow = row0 + wm * 64 + mi * 16 + (l >> 4) * 4 + r;
                C[(size_t)grow * DM + gcol] = acc[mi][ni][r];
            }
        }
}

// ---------------------------------------------------------------------------
// MFMA flash attention. Block = (64 q-rows, head); 4 waves, one 16-row band
// each. T14 async-stage: next K/V tile loaded to regs before compute of the
// current tile; T5 setprio around MFMA clusters. fp32 online softmax.
// q_b/k_b/v_b rows are 64 bf16 (128 B). LDS rows padded to 72 (2-way = free).
// ---------------------------------------------------------------------------
__global__ __launch_bounds__(256)
void attn_mfma(const unsigned short* __restrict__ qb,
               const unsigned short* __restrict__ kb,
               const unsigned short* __restrict__ vb,
               const float* __restrict__ gate,
               unsigned short* __restrict__ attnb)
{
    __shared__ __align__(16) unsigned short Qs[64][72];
    __shared__ __align__(16) unsigned short Ks[64][72];
    __shared__ __align__(16) unsigned short Vt[64][72];   // [d][k]
    __shared__ __align__(16) unsigned short Ps[64][72];

    // XCD swizzle: blocks of one head land on one XCD (K/V L2 reuse)
    const int sw   = (blockIdx.x & 7) * 64 + (blockIdx.x >> 3);
    const int head = sw >> 6;
    const int n0   = (sw & 63) * 64;
    const int t = threadIdx.x;
    const int wid = t >> 6;
    const int l = t & 63;
    const int l15 = l & 15, lh = l >> 4;

    // stage Q once
    #pragma unroll
    for (int it = 0; it < 2; ++it) {
        int idx = t + it * 256;
        int row = idx >> 3, c8 = (idx & 7) * 8;
        *(bf16x8*)&Qs[row][c8] =
            *(const bf16x8*)&qb[((size_t)(head * TN + n0 + row)) * 64 + c8];
    }

    f32x4 oacc[4];
    #pragma unroll
    for (int dt = 0; dt < 4; ++dt) oacc[dt] = (f32x4){0.f, 0.f, 0.f, 0.f};
    float mrow[4] = {-3.0e38f, -3.0e38f, -3.0e38f, -3.0e38f};
    float lrow[4] = {0.f, 0.f, 0.f, 0.f};

    const int p_base = MEM + n0;
    const int kstart = max(0, p_base - WINR);
    const int kend   = min(JTOT, p_base + 63 + WINR + 1);

    // T14 staging registers (K rows / V rows for one 64-tile)
    const int srow = t >> 3, sc8 = (t & 7) * 8;
    const int srow2 = (t + 256) >> 3, sc82 = ((t + 256) & 7) * 8;
    const int vj = t & 63, vd0 = (t >> 6) * 8;
    const int vj2 = (t + 256) & 63, vd02 = ((t + 256) >> 6) * 8;
    bf16x8 kr0, kr1, vr0, vr1;

    // prologue load of first tile
    kr0 = *(const bf16x8*)&kb[((size_t)head * JPAD + kstart + srow) * 64 + sc8];
    kr1 = *(const bf16x8*)&kb[((size_t)head * JPAD + kstart + srow2) * 64 + sc82];
    vr0 = *(const bf16x8*)&vb[((size_t)head * JPAD + kstart + vj) * 64 + vd0];
    vr1 = *(const bf16x8*)&vb[((size_t)head * JPAD + kstart + vj2) * 64 + vd02];

    for (int j0 = kstart; j0 < kend; j0 += 64) {
        __syncthreads();   // prior tile's LDS consumers done
        // write staged regs to LDS
        *(bf16x8*)&Ks[srow][sc8]   = kr0;
        *(bf16x8*)&Ks[srow2][sc82] = kr1;
        #pragma unroll
        for (int i = 0; i < 8; ++i) Vt[vd0 + i][vj]   = (unsigned short)vr0[i];
        #pragma unroll
        for (int i = 0; i < 8; ++i) Vt[vd02 + i][vj2] = (unsigned short)vr1[i];
        __syncthreads();

        // prefetch next tile into regs (overlaps compute below)
        if (j0 + 64 < kend) {
            int jn = j0 + 64;
            kr0 = *(const bf16x8*)&kb[((size_t)head * JPAD + jn + srow) * 64 + sc8];
            kr1 = *(const bf16x8*)&kb[((size_t)head * JPAD + jn + srow2) * 64 + sc82];
            vr0 = *(const bf16x8*)&vb[((size_t)head * JPAD + jn + vj) * 64 + vd0];
            vr1 = *(const bf16x8*)&vb[((size_t)head * JPAD + jn + vj2) * 64 + vd02];
        }

        // S band = Q[band] @ K^T
        f32x4 sacc[4];
        #pragma unroll
        for (int kt = 0; kt < 4; ++kt) sacc[kt] = (f32x4){0.f, 0.f, 0.f, 0.f};
        __builtin_amdgcn_s_setprio(1);
        #pragma unroll
        for (int s = 0; s < 2; ++s) {
            bf16x8 a = *(const bf16x8*)&Qs[wid * 16 + l15][s * 32 + lh * 8];
            #pragma unroll
            for (int kt = 0; kt < 4; ++kt) {
                bf16x8 b = *(const bf16x8*)&Ks[kt * 16 + l15][s * 32 + lh * 8];
                sacc[kt] = __builtin_amdgcn_mfma_f32_16x16x32_bf16(a, b, sacc[kt], 0, 0, 0);
            }
        }
        __builtin_amdgcn_s_setprio(0);

        // mask + online softmax (C/D: row q = lh*4+r, col k = kt*16+l15)
        #pragma unroll
        for (int r = 0; r < 4; ++r) {
            int pq = p_base + wid * 16 + lh * 4 + r;
            float sv[4];
            float tm = -3.0e38f;
            #pragma unroll
            for (int kt = 0; kt < 4; ++kt) {
                int j = j0 + kt * 16 + l15;
                int dist = pq - j;
                bool ok = (dist <= WINR) && (dist >= -WINR) && (j < JTOT);
                float val = ok ? sacc[kt][r] * QK_SCALE : -3.0e38f;
                sv[kt] = val;
                tm = fmaxf(tm, val);
            }
            #pragma unroll
            for (int off = 1; off < 16; off <<= 1) tm = fmaxf(tm, __shfl_xor(tm, off));
            float mnew = fmaxf(mrow[r], tm);
            float corr = __expf(mrow[r] - mnew);
            float rs = 0.f;
            #pragma unroll
            for (int kt = 0; kt < 4; ++kt) {
                float pe = (sv[kt] > -1.0e37f) ? __expf(sv[kt] - mnew) : 0.f;
                rs += pe;
                Ps[wid * 16 + lh * 4 + r][kt * 16 + l15] = f2bf(pe);
            }
            #pragma unroll
            for (int off = 1; off < 16; off <<= 1) rs += __shfl_xor(rs, off);
            lrow[r] = lrow[r] * corr + rs;
            mrow[r] = mnew;
            #pragma unroll
            for (int dt = 0; dt < 4; ++dt) oacc[dt][r] *= corr;
        }

        // O += P @ V
        __builtin_amdgcn_s_setprio(1);
        #pragma unroll
        for (int s = 0; s < 2; ++s) {
            bf16x8 a = *(const bf16x8*)&Ps[wid * 16 + l15][s * 32 + lh * 8];
            #pragma unroll
            for (int dt = 0; dt < 4; ++dt) {
                bf16x8 b = *(const bf16x8*)&Vt[dt * 16 + l15][s * 32 + lh * 8];
                oacc[dt] = __builtin_amdgcn_mfma_f32_16x16x32_bf16(a, b, oacc[dt], 0, 0, 0);
            }
        }
        __builtin_amdgcn_s_setprio(0);
    }

    // epilogue: normalize, gate, write merged-head bf16
    #pragma unroll
    for (int r = 0; r < 4; ++r) {
        int n = n0 + wid * 16 + lh * 4 + r;
        float inv = 1.0f / lrow[r];
        #pragma unroll
        for (int dt = 0; dt < 4; ++dt) {
            int col = head * 64 + dt * 16 + l15;
            float g = gate[(size_t)n * DM + col];
            attnb[(size_t)n * DM + col] = f2bf(oacc[dt][r] * inv * g);
        }
    }
}

// ---------------------------------------------------------------------------
extern "C" void kernel_launch(void* const* d_in, const int* in_sizes, int n_in,
                              void* d_out, int out_size, void* d_ws, size_t ws_size,
                              hipStream_t stream)
{
    const float* x     = (const float*)d_in[0];
    const float* Wq    = (const float*)d_in[1];
    const float* Wk    = (const float*)d_in[2];
    const float* Wv    = (const float*)d_in[3];
    const float* Wg    = (const float*)d_in[4];
    const float* bg    = (const float*)d_in[5];
    const float* Wo    = (const float*)d_in[6];
    const float* mem_k = (const float*)d_in[7];
    const float* mem_v = (const float*)d_in[8];
    const float* freqs = (const float*)d_in[9];

    // Workspace (~28.8 MB). attnb aliases Xb (Xb dead after gemm_qkvg_mfma;
    // attnb first written by attn_mfma).
    unsigned short* q_b = (unsigned short*)d_ws;               // [H][N][64] bf16
    unsigned short* k_b = q_b + (size_t)NH * TN * DHD;         // [H][JPAD][64] bf16
    unsigned short* v_b = k_b + (size_t)NH * JPAD * DHD;       // [H][JPAD][64] bf16
    unsigned short* Xb  = v_b + (size_t)NH * JPAD * DHD;       // [N][512] bf16
    unsigned short* attnb = Xb;                                // alias
    unsigned short* Wt  = Xb + (size_t)TN * DM;                // 5x[512][512] bf16
    float* graw = (float*)(Wt + (size_t)5 * DM * DM);          // [N][512] fp32 gate
    float2* tab = (float2*)(graw + (size_t)TN * DM);           // [4096][64] cos/sin

    // 0) prep: cast X, transpose weights, rope table, memory KV rows
    prep<<<dim3(2440), 256, 0, stream>>>(x, Xb, Wq, Wk, Wv, Wg, Wo, Wt,
                                         freqs, tab, mem_k, mem_v, k_b, v_b);

    // 1) Q/K/V/G projections (bf16 MFMA) + fused l2norm/RoPE/gate epilogues
    gemm_qkvg_mfma<<<dim3(TN / 128, DM / 128, 4), 256, 0, stream>>>(
        Xb, Wt, tab, bg, q_b, k_b, v_b, graw);

    // 2) MFMA local-window attention with gating (T14 + setprio)
    attn_mfma<<<dim3(512), 256, 0, stream>>>(q_b, k_b, v_b, graw, attnb);

    // 3) output projection (bf16 MFMA)
    gemm_out_mfma<<<dim3(TN / 128, DM / 128), 256, 0, stream>>>(
        attnb, Wt + (size_t)4 * DM * DM, (float*)d_out);
}

// Round 10
// 159.829 us; speedup vs baseline: 4.3440x; 1.0860x over previous
//
#include <hip/hip_runtime.h>
#include <math.h>

// Problem constants
#define TN 4096        // sequence length N
#define DM 512         // model dim D = H*DH
#define NH 8           // heads
#define DHD 64         // head dim
#define MEM 4          // memory slots M
#define WINR 512       // window radius
#define JTOT (TN + MEM)   // 4100 total keys
#define JPAD 4168      // padded key rows so tile over-reads stay in-bounds
#define QK_SCALE 10.0f
#define LDA 40         // GEMM LDS row stride (ushorts): 80B = 16B-aligned, 2-way banks

typedef __attribute__((ext_vector_type(8))) short bf16x8;   // 8 bf16 = 4 VGPRs (MFMA A/B frag)
typedef __attribute__((ext_vector_type(4))) float f32x4;    // MFMA C/D frag

// fp32 -> bf16 round-to-nearest-even
__device__ __forceinline__ unsigned short f2bf(float f) {
    unsigned u = __float_as_uint(f);
    u = (u + 0x7FFFu + ((u >> 16) & 1u)) >> 16;
    return (unsigned short)u;
}

// ---------------------------------------------------------------------------
// Sectioned prep kernel (one launch, 2440 blocks):
//   blocks    0..2047 : cast X fp32 -> bf16   (2048*256*4 = TN*DM)
//   blocks 2048..2367 : transpose+cast 5 weight matrices -> Wt (bf16, [n][k])
//   blocks 2368..2431 : rope table tab[n][d] = (cos,sin) fp32
//   blocks 2432..2439 : memory KV rows (l2norm mem_k, mem_v) as bf16
// ---------------------------------------------------------------------------
__global__ __launch_bounds__(256)
void prep(const float* __restrict__ X, unsigned short* __restrict__ Xb,
          const float* __restrict__ W0, const float* __restrict__ W1,
          const float* __restrict__ W2, const float* __restrict__ W3,
          const float* __restrict__ W4, unsigned short* __restrict__ T,
          const float* __restrict__ freqs, float2* __restrict__ tab,
          const float* __restrict__ mem_k, const float* __restrict__ mem_v,
          unsigned short* __restrict__ k_b, unsigned short* __restrict__ v_b)
{
    const int b = blockIdx.x;
    const int t = threadIdx.x;

    if (b < 2048) {                      // ---- cast X (full matrix)
        int idx = b * 256 + t;
        float4 v = *(const float4*)&X[(size_t)idx * 4];
        *(ushort4*)&Xb[(size_t)idx * 4] =
            make_ushort4(f2bf(v.x), f2bf(v.y), f2bf(v.z), f2bf(v.w));
    } else if (b < 2368) {               // ---- weight transpose+cast
        __shared__ unsigned short Ts[64][68];
        int bi = b - 2048;
        int sel = bi >> 6, tile = bi & 63;
        const float* __restrict__ W =
            (sel == 0) ? W0 : (sel == 1) ? W1 : (sel == 2) ? W2 : (sel == 3) ? W3 : W4;
        unsigned short* __restrict__ Wt = T + (size_t)sel * DM * DM;
        int r0 = (tile >> 3) * 64, c0 = (tile & 7) * 64;
        #pragma unroll
        for (int p = 0; p < 4; ++p) {
            int i  = p * 16 + (t >> 4);
            int j4 = (t & 15) * 4;
            float4 v = *(const float4*)&W[(size_t)(r0 + i) * DM + c0 + j4];
            Ts[i][j4 + 0] = f2bf(v.x); Ts[i][j4 + 1] = f2bf(v.y);
            Ts[i][j4 + 2] = f2bf(v.z); Ts[i][j4 + 3] = f2bf(v.w);
        }
        __syncthreads();
        #pragma unroll
        for (int p = 0; p < 4; ++p) {
            int oc  = p * 16 + (t >> 4);
            int or4 = (t & 15) * 4;
            *(ushort4*)&Wt[(size_t)(c0 + oc) * DM + r0 + or4] =
                make_ushort4(Ts[or4 + 0][oc], Ts[or4 + 1][oc],
                             Ts[or4 + 2][oc], Ts[or4 + 3][oc]);
        }
    } else if (b < 2432) {               // ---- rope cos/sin table
        int tid = (b - 2368) * 256 + t;
        #pragma unroll
        for (int e = 0; e < 16; ++e) {
            int id = e * 16384 + tid;
            float f = freqs[id];
            float sn, cs;
            sincosf(f, &sn, &cs);
            tab[id] = make_float2(cs, sn);
        }
    } else {                             // ---- memory KV rows
        int gw   = (b - 2432) * 4 + (t >> 6);
        int lane = t & 63;
        int h = gw >> 2, m = gw & 3;
        float kv = mem_k[(size_t)(h * MEM + m) * DHD + lane];
        float s = kv * kv;
        #pragma unroll
        for (int off = 1; off < 64; off <<= 1) s += __shfl_xor(s, off);
        kv = kv / fmaxf(sqrtf(s), 1e-12f);
        k_b[((size_t)h * JPAD + m) * 64 + lane] = f2bf(kv);
        v_b[((size_t)h * JPAD + m) * 64 + lane] =
            f2bf(mem_v[(size_t)(h * MEM + m) * DHD + lane]);
    }
}

// ---------------------------------------------------------------------------
// bf16 MFMA GEMM for Q/K/V/G projections with fused epilogues.
// LDS tiles [128][LDA=40]: 80B row stride -> b128 frag reads are 2-way (free);
// round-9's [128][32] (64B stride) was an 8-way conflict on every ds_read.
// ---------------------------------------------------------------------------
__global__ __launch_bounds__(256)
void gemm_qkvg_mfma(const unsigned short* __restrict__ Xb,
                    const unsigned short* __restrict__ Wt,
                    const float2* __restrict__ tab,
                    const float* __restrict__ bg,
                    unsigned short* __restrict__ q_b,
                    unsigned short* __restrict__ k_b,
                    unsigned short* __restrict__ v_b,
                    float* __restrict__ graw)
{
    __shared__ __align__(16) unsigned short As[128][LDA];
    __shared__ __align__(16) unsigned short Bs[128][LDA];
    const int sel = blockIdx.z;
    const unsigned short* __restrict__ Wsel = Wt + (size_t)sel * DM * DM;
    const int row0 = blockIdx.x * 128;
    const int col0 = blockIdx.y * 128;
    const int t = threadIdx.x;
    const int w = t >> 6, l = t & 63;
    const int wm = w >> 1, wn = w & 1;
    const int l15 = l & 15, lh = l >> 4;

    f32x4 acc[4][4];
    #pragma unroll
    for (int mi = 0; mi < 4; ++mi)
        #pragma unroll
        for (int ni = 0; ni < 4; ++ni)
            acc[mi][ni] = (f32x4){0.f, 0.f, 0.f, 0.f};

    for (int k0 = 0; k0 < DM; k0 += 32) {
        __syncthreads();
        #pragma unroll
        for (int cc = 0; cc < 2; ++cc) {
            int c = t + cc * 256;
            int row = c >> 2, k8 = c & 3;
            *(bf16x8*)&As[row][k8 * 8] =
                *(const bf16x8*)&Xb[(size_t)(row0 + row) * DM + k0 + k8 * 8];
            *(bf16x8*)&Bs[row][k8 * 8] =
                *(const bf16x8*)&Wsel[(size_t)(col0 + row) * DM + k0 + k8 * 8];
        }
        __syncthreads();

        bf16x8 af[4], bfr[4];
        #pragma unroll
        for (int mi = 0; mi < 4; ++mi)
            af[mi] = *(const bf16x8*)&As[wm * 64 + mi * 16 + l15][lh * 8];
        #pragma unroll
        for (int ni = 0; ni < 4; ++ni)
            bfr[ni] = *(const bf16x8*)&Bs[wn * 64 + ni * 16 + l15][lh * 8];
        #pragma unroll
        for (int mi = 0; mi < 4; ++mi)
            #pragma unroll
            for (int ni = 0; ni < 4; ++ni)
                acc[mi][ni] = __builtin_amdgcn_mfma_f32_16x16x32_bf16(
                    af[mi], bfr[ni], acc[mi][ni], 0, 0, 0);
    }

    if (sel <= 1) {
        // q/k: l2norm (shfl over l15) + RoPE + bf16 store. Head wave-constant.
        const int h = (col0 + wn * 64) >> 6;
        #pragma unroll
        for (int mi = 0; mi < 4; ++mi) {
            #pragma unroll
            for (int r = 0; r < 4; ++r) {
                float v0 = acc[mi][0][r], v1 = acc[mi][1][r];
                float v2 = acc[mi][2][r], v3 = acc[mi][3][r];
                float ss = v0 * v0 + v1 * v1 + v2 * v2 + v3 * v3;
                ss += __shfl_xor(ss, 1); ss += __shfl_xor(ss, 2);
                ss += __shfl_xor(ss, 4); ss += __shfl_xor(ss, 8);
                float inv = 1.0f / fmaxf(sqrtf(ss), 1e-12f);
                v0 *= inv; v1 *= inv; v2 *= inv; v3 *= inv;
                int n = row0 + wm * 64 + mi * 16 + lh * 4 + r;
                float2 t0 = tab[n * 64 + l15];
                float2 t1 = tab[n * 64 + 16 + l15];
                float o0 = v0 * t0.x - v2 * t0.y;
                float o1 = v1 * t1.x - v3 * t1.y;
                float o2 = v2 * t0.x + v0 * t0.y;
                float o3 = v3 * t1.x + v1 * t1.y;
                unsigned short* dst = (sel == 0)
                    ? &q_b[((size_t)h * TN + n) * 64]
                    : &k_b[((size_t)h * JPAD + MEM + n) * 64];
                dst[l15]      = f2bf(o0);
                dst[16 + l15] = f2bf(o1);
                dst[32 + l15] = f2bf(o2);
                dst[48 + l15] = f2bf(o3);
            }
        }
    } else if (sel == 2) {
        const int h = (col0 + wn * 64) >> 6;
        #pragma unroll
        for (int mi = 0; mi < 4; ++mi)
            #pragma unroll
            for (int ni = 0; ni < 4; ++ni) {
                int d = ni * 16 + l15;
                #pragma unroll
                for (int r = 0; r < 4; ++r) {
                    int grow = row0 + wm * 64 + mi * 16 + lh * 4 + r;
                    v_b[((size_t)h * JPAD + MEM + grow) * 64 + d] = f2bf(acc[mi][ni][r]);
                }
            }
    } else {
        #pragma unroll
        for (int mi = 0; mi < 4; ++mi)
            #pragma unroll
            for (int ni = 0; ni < 4; ++ni) {
                int gcol = col0 + wn * 64 + ni * 16 + l15;
                float bgv = bg[gcol];
                #pragma unroll
                for (int r = 0; r < 4; ++r) {
                    int grow = row0 + wm * 64 + mi * 16 + lh * 4 + r;
                    float g = acc[mi][ni][r] + bgv;
                    graw[(size_t)grow * DM + gcol] = 1.0f / (1.0f + __expf(-g));
                }
            }
    }
}

// ---------------------------------------------------------------------------
// bf16 MFMA GEMM: d_out = attnb @ Wo.  Same LDA=40 padding.
// ---------------------------------------------------------------------------
__global__ __launch_bounds__(256)
void gemm_out_mfma(const unsigned short* __restrict__ Ab,
                   const unsigned short* __restrict__ Wot,
                   float* __restrict__ C)
{
    __shared__ __align__(16) unsigned short As[128][LDA];
    __shared__ __align__(16) unsigned short Bs[128][LDA];
    const int row0 = blockIdx.x * 128;
    const int col0 = blockIdx.y * 128;
    const int t = threadIdx.x;
    const int w = t >> 6, l = t & 63;
    const int wm = w >> 1, wn = w & 1;

    f32x4 acc[4][4];
    #pragma unroll
    for (int mi = 0; mi < 4; ++mi)
        #pragma unroll
        for (int ni = 0; ni < 4; ++ni)
            acc[mi][ni] = (f32x4){0.f, 0.f, 0.f, 0.f};

    for (int k0 = 0; k0 < DM; k0 += 32) {
        __syncthreads();
        #pragma unroll
        for (int cc = 0; cc < 2; ++cc) {
            int c = t + cc * 256;
            int row = c >> 2, k8 = c & 3;
            *(bf16x8*)&As[row][k8 * 8] =
                *(const bf16x8*)&Ab[(size_t)(row0 + row) * DM + k0 + k8 * 8];
            *(bf16x8*)&Bs[row][k8 * 8] =
                *(const bf16x8*)&Wot[(size_t)(col0 + row) * DM + k0 + k8 * 8];
        }
        __syncthreads();

        bf16x8 af[4], bfr[4];
        #pragma unroll
        for (int mi = 0; mi < 4; ++mi)
            af[mi] = *(const bf16x8*)&As[wm * 64 + mi * 16 + (l & 15)][(l >> 4) * 8];
        #pragma unroll
        for (int ni = 0; ni < 4; ++ni)
            bfr[ni] = *(const bf16x8*)&Bs[wn * 64 + ni * 16 + (l & 15)][(l >> 4) * 8];
        #pragma unroll
        for (int mi = 0; mi < 4; ++mi)
            #pragma unroll
            for (int ni = 0; ni < 4; ++ni)
                acc[mi][ni] = __builtin_amdgcn_mfma_f32_16x16x32_bf16(
                    af[mi], bfr[ni], acc[mi][ni], 0, 0, 0);
    }

    #pragma unroll
    for (int mi = 0; mi < 4; ++mi)
        #pragma unroll
        for (int ni = 0; ni < 4; ++ni) {
            int gcol = col0 + wn * 64 + ni * 16 + (l & 15);
            #pragma unroll
            for (int r = 0; r < 4; ++r) {
                int grow = row0 + wm * 64 + mi * 16 + (l >> 4) * 4 + r;
                C[(size_t)grow * DM + gcol] = acc[mi][ni][r];
            }
        }
}

// ---------------------------------------------------------------------------
// MFMA flash attention with FIXED-MAX softmax: logits = 10*dot(q̂,k̂) <= ~10.1,
// so P = exp(s - 10) is mathematically identical to max-subtracted softmax
// (ratio unchanged; no overflow; min e^-20 exact in fp32). Eliminates online
// max/rescale entirely; row-sum reduced ONCE in the epilogue (lane partials).
// T14 reg prefetch + T5 setprio kept from round 9 (A/B: 53.0 -> 49.6 µs).
// ---------------------------------------------------------------------------
__global__ __launch_bounds__(256)
void attn_mfma(const unsigned short* __restrict__ qb,
               const unsigned short* __restrict__ kb,
               const unsigned short* __restrict__ vb,
               const float* __restrict__ gate,
               unsigned short* __restrict__ attnb)
{
    __shared__ __align__(16) unsigned short Qs[64][72];
    __shared__ __align__(16) unsigned short Ks[64][72];
    __shared__ __align__(16) unsigned short Vt[64][72];   // [d][k]
    __shared__ __align__(16) unsigned short Ps[64][72];

    // XCD swizzle: blocks of one head land on one XCD (K/V L2 reuse)
    const int sw   = (blockIdx.x & 7) * 64 + (blockIdx.x >> 3);
    const int head = sw >> 6;
    const int n0   = (sw & 63) * 64;
    const int t = threadIdx.x;
    const int wid = t >> 6;
    const int l = t & 63;
    const int l15 = l & 15, lh = l >> 4;

    // stage Q once
    #pragma unroll
    for (int it = 0; it < 2; ++it) {
        int idx = t + it * 256;
        int row = idx >> 3, c8 = (idx & 7) * 8;
        *(bf16x8*)&Qs[row][c8] =
            *(const bf16x8*)&qb[((size_t)(head * TN + n0 + row)) * 64 + c8];
    }

    f32x4 oacc[4];
    #pragma unroll
    for (int dt = 0; dt < 4; ++dt) oacc[dt] = (f32x4){0.f, 0.f, 0.f, 0.f};
    float lpart[4] = {0.f, 0.f, 0.f, 0.f};   // per-lane partial row sums

    const int p_base = MEM + n0;
    const int kstart = max(0, p_base - WINR);
    const int kend   = min(JTOT, p_base + 63 + WINR + 1);

    // T14 staging registers (K rows / V rows for one 64-tile)
    const int srow = t >> 3, sc8 = (t & 7) * 8;
    const int srow2 = (t + 256) >> 3, sc82 = ((t + 256) & 7) * 8;
    const int vj = t & 63, vd0 = (t >> 6) * 8;
    const int vj2 = (t + 256) & 63, vd02 = ((t + 256) >> 6) * 8;
    bf16x8 kr0, kr1, vr0, vr1;

    kr0 = *(const bf16x8*)&kb[((size_t)head * JPAD + kstart + srow) * 64 + sc8];
    kr1 = *(const bf16x8*)&kb[((size_t)head * JPAD + kstart + srow2) * 64 + sc82];
    vr0 = *(const bf16x8*)&vb[((size_t)head * JPAD + kstart + vj) * 64 + vd0];
    vr1 = *(const bf16x8*)&vb[((size_t)head * JPAD + kstart + vj2) * 64 + vd02];

    for (int j0 = kstart; j0 < kend; j0 += 64) {
        __syncthreads();
        *(bf16x8*)&Ks[srow][sc8]   = kr0;
        *(bf16x8*)&Ks[srow2][sc82] = kr1;
        #pragma unroll
        for (int i = 0; i < 8; ++i) Vt[vd0 + i][vj]   = (unsigned short)vr0[i];
        #pragma unroll
        for (int i = 0; i < 8; ++i) Vt[vd02 + i][vj2] = (unsigned short)vr1[i];
        __syncthreads();

        if (j0 + 64 < kend) {
            int jn = j0 + 64;
            kr0 = *(const bf16x8*)&kb[((size_t)head * JPAD + jn + srow) * 64 + sc8];
            kr1 = *(const bf16x8*)&kb[((size_t)head * JPAD + jn + srow2) * 64 + sc82];
            vr0 = *(const bf16x8*)&vb[((size_t)head * JPAD + jn + vj) * 64 + vd0];
            vr1 = *(const bf16x8*)&vb[((size_t)head * JPAD + jn + vj2) * 64 + vd02];
        }

        // S band = Q[band] @ K^T
        f32x4 sacc[4];
        #pragma unroll
        for (int kt = 0; kt < 4; ++kt) sacc[kt] = (f32x4){0.f, 0.f, 0.f, 0.f};
        __builtin_amdgcn_s_setprio(1);
        #pragma unroll
        for (int s = 0; s < 2; ++s) {
            bf16x8 a = *(const bf16x8*)&Qs[wid * 16 + l15][s * 32 + lh * 8];
            #pragma unroll
            for (int kt = 0; kt < 4; ++kt) {
                bf16x8 b = *(const bf16x8*)&Ks[kt * 16 + l15][s * 32 + lh * 8];
                sacc[kt] = __builtin_amdgcn_mfma_f32_16x16x32_bf16(a, b, sacc[kt], 0, 0, 0);
            }
        }
        __builtin_amdgcn_s_setprio(0);

        // fixed-max softmax: P = exp(10*s - 10), masked -> 0
        #pragma unroll
        for (int r = 0; r < 4; ++r) {
            int pq = p_base + wid * 16 + lh * 4 + r;
            #pragma unroll
            for (int kt = 0; kt < 4; ++kt) {
                int j = j0 + kt * 16 + l15;
                int dist = pq - j;
                bool ok = (dist <= WINR) && (dist >= -WINR) && (j < JTOT);
                float pe = ok ? __expf(sacc[kt][r] * QK_SCALE - 10.0f) : 0.f;
                lpart[r] += pe;
                Ps[wid * 16 + lh * 4 + r][kt * 16 + l15] = f2bf(pe);
            }
        }

        // O += P @ V (Ps rows are wave-own: no barrier needed, lgkmcnt suffices)
        __builtin_amdgcn_s_setprio(1);
        #pragma unroll
        for (int s = 0; s < 2; ++s) {
            bf16x8 a = *(const bf16x8*)&Ps[wid * 16 + l15][s * 32 + lh * 8];
            #pragma unroll
            for (int dt = 0; dt < 4; ++dt) {
                bf16x8 b = *(const bf16x8*)&Vt[dt * 16 + l15][s * 32 + lh * 8];
                oacc[dt] = __builtin_amdgcn_mfma_f32_16x16x32_bf16(a, b, oacc[dt], 0, 0, 0);
            }
        }
        __builtin_amdgcn_s_setprio(0);
    }

    // epilogue: single row-sum reduce (over l15 lanes), normalize, gate, store
    #pragma unroll
    for (int r = 0; r < 4; ++r) {
        float rs = lpart[r];
        rs += __shfl_xor(rs, 1); rs += __shfl_xor(rs, 2);
        rs += __shfl_xor(rs, 4); rs += __shfl_xor(rs, 8);
        float inv = 1.0f / rs;
        int n = n0 + wid * 16 + lh * 4 + r;
        #pragma unroll
        for (int dt = 0; dt < 4; ++dt) {
            int col = head * 64 + dt * 16 + l15;
            float g = gate[(size_t)n * DM + col];
            attnb[(size_t)n * DM + col] = f2bf(oacc[dt][r] * inv * g);
        }
    }
}

// ---------------------------------------------------------------------------
extern "C" void kernel_launch(void* const* d_in, const int* in_sizes, int n_in,
                              void* d_out, int out_size, void* d_ws, size_t ws_size,
                              hipStream_t stream)
{
    const float* x     = (const float*)d_in[0];
    const float* Wq    = (const float*)d_in[1];
    const float* Wk    = (const float*)d_in[2];
    const float* Wv    = (const float*)d_in[3];
    const float* Wg    = (const float*)d_in[4];
    const float* bg    = (const float*)d_in[5];
    const float* Wo    = (const float*)d_in[6];
    const float* mem_k = (const float*)d_in[7];
    const float* mem_v = (const float*)d_in[8];
    const float* freqs = (const float*)d_in[9];

    // Workspace (~28.8 MB). attnb aliases Xb (Xb dead after gemm_qkvg_mfma;
    // attnb first written by attn_mfma).
    unsigned short* q_b = (unsigned short*)d_ws;               // [H][N][64] bf16
    unsigned short* k_b = q_b + (size_t)NH * TN * DHD;         // [H][JPAD][64] bf16
    unsigned short* v_b = k_b + (size_t)NH * JPAD * DHD;       // [H][JPAD][64] bf16
    unsigned short* Xb  = v_b + (size_t)NH * JPAD * DHD;       // [N][512] bf16
    unsigned short* attnb = Xb;                                // alias
    unsigned short* Wt  = Xb + (size_t)TN * DM;                // 5x[512][512] bf16
    float* graw = (float*)(Wt + (size_t)5 * DM * DM);          // [N][512] fp32 gate
    float2* tab = (float2*)(graw + (size_t)TN * DM);           // [4096][64] cos/sin

    // 0) prep: cast X, transpose weights, rope table, memory KV rows
    prep<<<dim3(2440), 256, 0, stream>>>(x, Xb, Wq, Wk, Wv, Wg, Wo, Wt,
                                         freqs, tab, mem_k, mem_v, k_b, v_b);

    // 1) Q/K/V/G projections (bf16 MFMA) + fused l2norm/RoPE/gate epilogues
    gemm_qkvg_mfma<<<dim3(TN / 128, DM / 128, 4), 256, 0, stream>>>(
        Xb, Wt, tab, bg, q_b, k_b, v_b, graw);

    // 2) MFMA local-window attention with gating (fixed-max softmax)
    attn_mfma<<<dim3(512), 256, 0, stream>>>(q_b, k_b, v_b, graw, attnb);

    // 3) output projection (bf16 MFMA)
    gemm_out_mfma<<<dim3(TN / 128, DM / 128), 256, 0, stream>>>(
        attnb, Wt + (size_t)4 * DM * DM, (float*)d_out);
}

// Round 11
// 157.022 us; speedup vs baseline: 4.4216x; 1.0179x over previous
//
#include <hip/hip_runtime.h>
#include <math.h>

// Problem constants
#define TN 4096        // sequence length N
#define DM 512         // model dim D = H*DH
#define NH 8           // heads
#define DHD 64         // head dim
#define MEM 4          // memory slots M
#define WINR 512       // window radius
#define JTOT (TN + MEM)   // 4100 total keys
#define JPAD 4168      // padded key rows so tile over-reads stay in-bounds
#define QK_SCALE 10.0f
#define LDA 40         // GEMM LDS row stride (ushorts)

typedef __attribute__((ext_vector_type(8))) short bf16x8;   // 8 bf16 = 4 VGPRs (MFMA A/B frag)
typedef __attribute__((ext_vector_type(4))) float f32x4;    // MFMA C/D frag

// fp32 -> bf16 round-to-nearest-even
__device__ __forceinline__ unsigned short f2bf(float f) {
    unsigned u = __float_as_uint(f);
    u = (u + 0x7FFFu + ((u >> 16) & 1u)) >> 16;
    return (unsigned short)u;
}

// ---------------------------------------------------------------------------
// Sectioned prep kernel (one launch, 2440 blocks):
//   blocks    0..2047 : cast X fp32 -> bf16   (2048*256*4 = TN*DM)
//   blocks 2048..2367 : transpose+cast 5 weight matrices -> Wt (bf16, [n][k])
//   blocks 2368..2431 : rope table tab[n][d] = (cos,sin) fp32
//   blocks 2432..2439 : memory KV rows (l2norm mem_k, mem_v) as bf16
// ---------------------------------------------------------------------------
__global__ __launch_bounds__(256)
void prep(const float* __restrict__ X, unsigned short* __restrict__ Xb,
          const float* __restrict__ W0, const float* __restrict__ W1,
          const float* __restrict__ W2, const float* __restrict__ W3,
          const float* __restrict__ W4, unsigned short* __restrict__ T,
          const float* __restrict__ freqs, float2* __restrict__ tab,
          const float* __restrict__ mem_k, const float* __restrict__ mem_v,
          unsigned short* __restrict__ k_b, unsigned short* __restrict__ v_b)
{
    const int b = blockIdx.x;
    const int t = threadIdx.x;

    if (b < 2048) {                      // ---- cast X (full matrix)
        int idx = b * 256 + t;
        float4 v = *(const float4*)&X[(size_t)idx * 4];
        *(ushort4*)&Xb[(size_t)idx * 4] =
            make_ushort4(f2bf(v.x), f2bf(v.y), f2bf(v.z), f2bf(v.w));
    } else if (b < 2368) {               // ---- weight transpose+cast
        __shared__ unsigned short Ts[64][68];
        int bi = b - 2048;
        int sel = bi >> 6, tile = bi & 63;
        const float* __restrict__ W =
            (sel == 0) ? W0 : (sel == 1) ? W1 : (sel == 2) ? W2 : (sel == 3) ? W3 : W4;
        unsigned short* __restrict__ Wt = T + (size_t)sel * DM * DM;
        int r0 = (tile >> 3) * 64, c0 = (tile & 7) * 64;
        #pragma unroll
        for (int p = 0; p < 4; ++p) {
            int i  = p * 16 + (t >> 4);
            int j4 = (t & 15) * 4;
            float4 v = *(const float4*)&W[(size_t)(r0 + i) * DM + c0 + j4];
            Ts[i][j4 + 0] = f2bf(v.x); Ts[i][j4 + 1] = f2bf(v.y);
            Ts[i][j4 + 2] = f2bf(v.z); Ts[i][j4 + 3] = f2bf(v.w);
        }
        __syncthreads();
        #pragma unroll
        for (int p = 0; p < 4; ++p) {
            int oc  = p * 16 + (t >> 4);
            int or4 = (t & 15) * 4;
            *(ushort4*)&Wt[(size_t)(c0 + oc) * DM + r0 + or4] =
                make_ushort4(Ts[or4 + 0][oc], Ts[or4 + 1][oc],
                             Ts[or4 + 2][oc], Ts[or4 + 3][oc]);
        }
    } else if (b < 2432) {               // ---- rope cos/sin table
        int tid = (b - 2368) * 256 + t;
        #pragma unroll
        for (int e = 0; e < 16; ++e) {
            int id = e * 16384 + tid;
            float f = freqs[id];
            float sn, cs;
            sincosf(f, &sn, &cs);
            tab[id] = make_float2(cs, sn);
        }
    } else {                             // ---- memory KV rows
        int gw   = (b - 2432) * 4 + (t >> 6);
        int lane = t & 63;
        int h = gw >> 2, m = gw & 3;
        float kv = mem_k[(size_t)(h * MEM + m) * DHD + lane];
        float s = kv * kv;
        #pragma unroll
        for (int off = 1; off < 64; off <<= 1) s += __shfl_xor(s, off);
        kv = kv / fmaxf(sqrtf(s), 1e-12f);
        k_b[((size_t)h * JPAD + m) * 64 + lane] = f2bf(kv);
        v_b[((size_t)h * JPAD + m) * 64 + lane] =
            f2bf(mem_v[(size_t)(h * MEM + m) * DHD + lane]);
    }
}

// ---------------------------------------------------------------------------
// bf16 MFMA GEMM for Q/K/V/G projections with fused epilogues (unchanged).
// ---------------------------------------------------------------------------
__global__ __launch_bounds__(256)
void gemm_qkvg_mfma(const unsigned short* __restrict__ Xb,
                    const unsigned short* __restrict__ Wt,
                    const float2* __restrict__ tab,
                    const float* __restrict__ bg,
                    unsigned short* __restrict__ q_b,
                    unsigned short* __restrict__ k_b,
                    unsigned short* __restrict__ v_b,
                    float* __restrict__ graw)
{
    __shared__ __align__(16) unsigned short As[128][LDA];
    __shared__ __align__(16) unsigned short Bs[128][LDA];
    const int sel = blockIdx.z;
    const unsigned short* __restrict__ Wsel = Wt + (size_t)sel * DM * DM;
    const int row0 = blockIdx.x * 128;
    const int col0 = blockIdx.y * 128;
    const int t = threadIdx.x;
    const int w = t >> 6, l = t & 63;
    const int wm = w >> 1, wn = w & 1;
    const int l15 = l & 15, lh = l >> 4;

    f32x4 acc[4][4];
    #pragma unroll
    for (int mi = 0; mi < 4; ++mi)
        #pragma unroll
        for (int ni = 0; ni < 4; ++ni)
            acc[mi][ni] = (f32x4){0.f, 0.f, 0.f, 0.f};

    for (int k0 = 0; k0 < DM; k0 += 32) {
        __syncthreads();
        #pragma unroll
        for (int cc = 0; cc < 2; ++cc) {
            int c = t + cc * 256;
            int row = c >> 2, k8 = c & 3;
            *(bf16x8*)&As[row][k8 * 8] =
                *(const bf16x8*)&Xb[(size_t)(row0 + row) * DM + k0 + k8 * 8];
            *(bf16x8*)&Bs[row][k8 * 8] =
                *(const bf16x8*)&Wsel[(size_t)(col0 + row) * DM + k0 + k8 * 8];
        }
        __syncthreads();

        bf16x8 af[4], bfr[4];
        #pragma unroll
        for (int mi = 0; mi < 4; ++mi)
            af[mi] = *(const bf16x8*)&As[wm * 64 + mi * 16 + l15][lh * 8];
        #pragma unroll
        for (int ni = 0; ni < 4; ++ni)
            bfr[ni] = *(const bf16x8*)&Bs[wn * 64 + ni * 16 + l15][lh * 8];
        #pragma unroll
        for (int mi = 0; mi < 4; ++mi)
            #pragma unroll
            for (int ni = 0; ni < 4; ++ni)
                acc[mi][ni] = __builtin_amdgcn_mfma_f32_16x16x32_bf16(
                    af[mi], bfr[ni], acc[mi][ni], 0, 0, 0);
    }

    if (sel <= 1) {
        const int h = (col0 + wn * 64) >> 6;
        #pragma unroll
        for (int mi = 0; mi < 4; ++mi) {
            #pragma unroll
            for (int r = 0; r < 4; ++r) {
                float v0 = acc[mi][0][r], v1 = acc[mi][1][r];
                float v2 = acc[mi][2][r], v3 = acc[mi][3][r];
                float ss = v0 * v0 + v1 * v1 + v2 * v2 + v3 * v3;
                ss += __shfl_xor(ss, 1); ss += __shfl_xor(ss, 2);
                ss += __shfl_xor(ss, 4); ss += __shfl_xor(ss, 8);
                float inv = 1.0f / fmaxf(sqrtf(ss), 1e-12f);
                v0 *= inv; v1 *= inv; v2 *= inv; v3 *= inv;
                int n = row0 + wm * 64 + mi * 16 + lh * 4 + r;
                float2 t0 = tab[n * 64 + l15];
                float2 t1 = tab[n * 64 + 16 + l15];
                float o0 = v0 * t0.x - v2 * t0.y;
                float o1 = v1 * t1.x - v3 * t1.y;
                float o2 = v2 * t0.x + v0 * t0.y;
                float o3 = v3 * t1.x + v1 * t1.y;
                unsigned short* dst = (sel == 0)
                    ? &q_b[((size_t)h * TN + n) * 64]
                    : &k_b[((size_t)h * JPAD + MEM + n) * 64];
                dst[l15]      = f2bf(o0);
                dst[16 + l15] = f2bf(o1);
                dst[32 + l15] = f2bf(o2);
                dst[48 + l15] = f2bf(o3);
            }
        }
    } else if (sel == 2) {
        const int h = (col0 + wn * 64) >> 6;
        #pragma unroll
        for (int mi = 0; mi < 4; ++mi)
            #pragma unroll
            for (int ni = 0; ni < 4; ++ni) {
                int d = ni * 16 + l15;
                #pragma unroll
                for (int r = 0; r < 4; ++r) {
                    int grow = row0 + wm * 64 + mi * 16 + lh * 4 + r;
                    v_b[((size_t)h * JPAD + MEM + grow) * 64 + d] = f2bf(acc[mi][ni][r]);
                }
            }
    } else {
        #pragma unroll
        for (int mi = 0; mi < 4; ++mi)
            #pragma unroll
            for (int ni = 0; ni < 4; ++ni) {
                int gcol = col0 + wn * 64 + ni * 16 + l15;
                float bgv = bg[gcol];
                #pragma unroll
                for (int r = 0; r < 4; ++r) {
                    int grow = row0 + wm * 64 + mi * 16 + lh * 4 + r;
                    float g = acc[mi][ni][r] + bgv;
                    graw[(size_t)grow * DM + gcol] = 1.0f / (1.0f + __expf(-g));
                }
            }
    }
}

// ---------------------------------------------------------------------------
// bf16 MFMA GEMM: d_out = attnb @ Wo (unchanged).
// ---------------------------------------------------------------------------
__global__ __launch_bounds__(256)
void gemm_out_mfma(const unsigned short* __restrict__ Ab,
                   const unsigned short* __restrict__ Wot,
                   float* __restrict__ C)
{
    __shared__ __align__(16) unsigned short As[128][LDA];
    __shared__ __align__(16) unsigned short Bs[128][LDA];
    const int row0 = blockIdx.x * 128;
    const int col0 = blockIdx.y * 128;
    const int t = threadIdx.x;
    const int w = t >> 6, l = t & 63;
    const int wm = w >> 1, wn = w & 1;

    f32x4 acc[4][4];
    #pragma unroll
    for (int mi = 0; mi < 4; ++mi)
        #pragma unroll
        for (int ni = 0; ni < 4; ++ni)
            acc[mi][ni] = (f32x4){0.f, 0.f, 0.f, 0.f};

    for (int k0 = 0; k0 < DM; k0 += 32) {
        __syncthreads();
        #pragma unroll
        for (int cc = 0; cc < 2; ++cc) {
            int c = t + cc * 256;
            int row = c >> 2, k8 = c & 3;
            *(bf16x8*)&As[row][k8 * 8] =
                *(const bf16x8*)&Ab[(size_t)(row0 + row) * DM + k0 + k8 * 8];
            *(bf16x8*)&Bs[row][k8 * 8] =
                *(const bf16x8*)&Wot[(size_t)(col0 + row) * DM + k0 + k8 * 8];
        }
        __syncthreads();

        bf16x8 af[4], bfr[4];
        #pragma unroll
        for (int mi = 0; mi < 4; ++mi)
            af[mi] = *(const bf16x8*)&As[wm * 64 + mi * 16 + (l & 15)][(l >> 4) * 8];
        #pragma unroll
        for (int ni = 0; ni < 4; ++ni)
            bfr[ni] = *(const bf16x8*)&Bs[wn * 64 + ni * 16 + (l & 15)][(l >> 4) * 8];
        #pragma unroll
        for (int mi = 0; mi < 4; ++mi)
            #pragma unroll
            for (int ni = 0; ni < 4; ++ni)
                acc[mi][ni] = __builtin_amdgcn_mfma_f32_16x16x32_bf16(
                    af[mi], bfr[ni], acc[mi][ni], 0, 0, 0);
    }

    #pragma unroll
    for (int mi = 0; mi < 4; ++mi)
        #pragma unroll
        for (int ni = 0; ni < 4; ++ni) {
            int gcol = col0 + wn * 64 + ni * 16 + (l & 15);
            #pragma unroll
            for (int r = 0; r < 4; ++r) {
                int grow = row0 + wm * 64 + mi * 16 + (l >> 4) * 4 + r;
                C[(size_t)grow * DM + gcol] = acc[mi][ni][r];
            }
        }
}

// ---------------------------------------------------------------------------
// MFMA flash attention, 512 threads = 2 independent j-groups of 4 waves.
// Fixed-max softmax (validated r10) makes j-tile contributions order-free, so
// group g handles tiles g, g+2, g+4, ... and partial (O, lsum) are combined
// once in the epilogue via LDS. Occupancy ceiling 25% -> 50% (grid was the
// limiter: 512 blocks = 2/CU; now 8 waves/block -> 16 waves/CU).
// LDS: 7 x 64x72 ushort tiles = 64.5 KB -> still 2 blocks/CU.
// ---------------------------------------------------------------------------
#define TILE_US (64 * 72)
__global__ __launch_bounds__(512)
void attn_mfma(const unsigned short* __restrict__ qb,
               const unsigned short* __restrict__ kb,
               const unsigned short* __restrict__ vb,
               const float* __restrict__ gate,
               unsigned short* __restrict__ attnb)
{
    __shared__ __align__(16) unsigned short smem[TILE_US * 7];
    // layout: Qs | Ks0 | Ks1 | Vt0 | Vt1 | Ps0 | Ps1
    unsigned short* Qs = smem;
    #define KS(g) (smem + TILE_US * (1 + (g)))
    #define VT(g) (smem + TILE_US * (3 + (g)))
    #define PS(g) (smem + TILE_US * (5 + (g)))

    // XCD swizzle: blocks of one head land on one XCD (K/V L2 reuse)
    const int sw   = (blockIdx.x & 7) * 64 + (blockIdx.x >> 3);
    const int head = sw >> 6;
    const int n0   = (sw & 63) * 64;
    const int t   = threadIdx.x;
    const int g   = t >> 8;          // j-group 0/1
    const int tig = t & 255;         // thread-in-group
    const int wid = (t >> 6) & 3;    // q-band within group
    const int l   = t & 63;
    const int l15 = l & 15, lh = l >> 4;

    // stage Q once (512 threads cover 64 rows x 8 chunks)
    {
        int row = t >> 3, c8 = (t & 7) * 8;
        *(bf16x8*)&Qs[row * 72 + c8] =
            *(const bf16x8*)&qb[((size_t)(head * TN + n0 + row)) * 64 + c8];
    }

    f32x4 oacc[4];
    #pragma unroll
    for (int dt = 0; dt < 4; ++dt) oacc[dt] = (f32x4){0.f, 0.f, 0.f, 0.f};
    float lpart[4] = {0.f, 0.f, 0.f, 0.f};

    const int p_base = MEM + n0;
    const int kstart = max(0, p_base - WINR);
    const int kend   = min(JTOT, p_base + 63 + WINR + 1);
    const int ntiles = (kend - kstart + 63) >> 6;
    const int niter  = (ntiles + 1) >> 1;

    // staging addresses (within group: 256 threads stage one 64-tile)
    const int srow = tig >> 3, sc8 = (tig & 7) * 8;
    const int srow2 = (tig + 256) >> 3, sc82 = ((tig + 256) & 7) * 8;
    const int vj = tig & 63, vd0 = (tig >> 6) * 8;
    const int vj2 = (tig + 256) & 63, vd02 = ((tig + 256) >> 6) * 8;
    bf16x8 kr0, kr1, vr0, vr1;

    // prologue: load this group's first tile (tile index g; ntiles >= 2 always)
    int tj = g;
    {
        int j0 = kstart + tj * 64;
        kr0 = *(const bf16x8*)&kb[((size_t)head * JPAD + j0 + srow) * 64 + sc8];
        kr1 = *(const bf16x8*)&kb[((size_t)head * JPAD + j0 + srow2) * 64 + sc82];
        vr0 = *(const bf16x8*)&vb[((size_t)head * JPAD + j0 + vj) * 64 + vd0];
        vr1 = *(const bf16x8*)&vb[((size_t)head * JPAD + j0 + vj2) * 64 + vd02];
    }

    for (int it = 0; it < niter; ++it) {
        bool valid = (tj < ntiles);
        __syncthreads();   // prior iteration's LDS consumers done
        if (valid) {
            *(bf16x8*)&KS(g)[srow * 72 + sc8]   = kr0;
            *(bf16x8*)&KS(g)[srow2 * 72 + sc82] = kr1;
            #pragma unroll
            for (int i = 0; i < 8; ++i) VT(g)[(vd0 + i) * 72 + vj]   = (unsigned short)vr0[i];
            #pragma unroll
            for (int i = 0; i < 8; ++i) VT(g)[(vd02 + i) * 72 + vj2] = (unsigned short)vr1[i];
        }
        __syncthreads();

        if (valid) {
            int j0 = kstart + tj * 64;
            if (tj + 2 < ntiles) {
                int jn = kstart + (tj + 2) * 64;
                kr0 = *(const bf16x8*)&kb[((size_t)head * JPAD + jn + srow) * 64 + sc8];
                kr1 = *(const bf16x8*)&kb[((size_t)head * JPAD + jn + srow2) * 64 + sc82];
                vr0 = *(const bf16x8*)&vb[((size_t)head * JPAD + jn + vj) * 64 + vd0];
                vr1 = *(const bf16x8*)&vb[((size_t)head * JPAD + jn + vj2) * 64 + vd02];
            }

            // S band = Q[band] @ K^T
            f32x4 sacc[4];
            #pragma unroll
            for (int kt = 0; kt < 4; ++kt) sacc[kt] = (f32x4){0.f, 0.f, 0.f, 0.f};
            __builtin_amdgcn_s_setprio(1);
            #pragma unroll
            for (int s = 0; s < 2; ++s) {
                bf16x8 a = *(const bf16x8*)&Qs[(wid * 16 + l15) * 72 + s * 32 + lh * 8];
                #pragma unroll
                for (int kt = 0; kt < 4; ++kt) {
                    bf16x8 b = *(const bf16x8*)&KS(g)[(kt * 16 + l15) * 72 + s * 32 + lh * 8];
                    sacc[kt] = __builtin_amdgcn_mfma_f32_16x16x32_bf16(a, b, sacc[kt], 0, 0, 0);
                }
            }
            __builtin_amdgcn_s_setprio(0);

            // fixed-max softmax: P = exp(10*s - 10), masked -> 0
            #pragma unroll
            for (int r = 0; r < 4; ++r) {
                int pq = p_base + wid * 16 + lh * 4 + r;
                #pragma unroll
                for (int kt = 0; kt < 4; ++kt) {
                    int j = j0 + kt * 16 + l15;
                    int dist = pq - j;
                    bool ok = (dist <= WINR) && (dist >= -WINR) && (j < JTOT);
                    float pe = ok ? __expf(sacc[kt][r] * QK_SCALE - 10.0f) : 0.f;
                    lpart[r] += pe;
                    PS(g)[(wid * 16 + lh * 4 + r) * 72 + kt * 16 + l15] = f2bf(pe);
                }
            }

            // O += P @ V (Ps rows wave-own; lgkmcnt ordering suffices)
            __builtin_amdgcn_s_setprio(1);
            #pragma unroll
            for (int s = 0; s < 2; ++s) {
                bf16x8 a = *(const bf16x8*)&PS(g)[(wid * 16 + l15) * 72 + s * 32 + lh * 8];
                #pragma unroll
                for (int dt = 0; dt < 4; ++dt) {
                    bf16x8 b = *(const bf16x8*)&VT(g)[(dt * 16 + l15) * 72 + s * 32 + lh * 8];
                    oacc[dt] = __builtin_amdgcn_mfma_f32_16x16x32_bf16(a, b, oacc[dt], 0, 0, 0);
                }
            }
            __builtin_amdgcn_s_setprio(0);
        }
        tj += 2;
    }

    // ---- combine group partials (fbuf aliases smem; all tiles dead) ----
    float* fbuf = (float*)smem;   // 256 threads x 21 floats = 21.5 KB
    __syncthreads();
    if (g == 1) {
        #pragma unroll
        for (int dt = 0; dt < 4; ++dt)
            #pragma unroll
            for (int r = 0; r < 4; ++r)
                fbuf[tig * 21 + dt * 4 + r] = oacc[dt][r];
        #pragma unroll
        for (int r = 0; r < 4; ++r) fbuf[tig * 21 + 16 + r] = lpart[r];
    }
    __syncthreads();
    if (g == 0) {
        #pragma unroll
        for (int dt = 0; dt < 4; ++dt)
            #pragma unroll
            for (int r = 0; r < 4; ++r)
                oacc[dt][r] += fbuf[tig * 21 + dt * 4 + r];
        #pragma unroll
        for (int r = 0; r < 4; ++r) lpart[r] += fbuf[tig * 21 + 16 + r];

        // epilogue: row-sum reduce over l15 lanes, normalize, gate, store
        #pragma unroll
        for (int r = 0; r < 4; ++r) {
            float rs = lpart[r];
            rs += __shfl_xor(rs, 1); rs += __shfl_xor(rs, 2);
            rs += __shfl_xor(rs, 4); rs += __shfl_xor(rs, 8);
            float inv = 1.0f / rs;
            int n = n0 + wid * 16 + lh * 4 + r;
            #pragma unroll
            for (int dt = 0; dt < 4; ++dt) {
                int col = head * 64 + dt * 16 + l15;
                float gv = gate[(size_t)n * DM + col];
                attnb[(size_t)n * DM + col] = f2bf(oacc[dt][r] * inv * gv);
            }
        }
    }
}

// ---------------------------------------------------------------------------
extern "C" void kernel_launch(void* const* d_in, const int* in_sizes, int n_in,
                              void* d_out, int out_size, void* d_ws, size_t ws_size,
                              hipStream_t stream)
{
    const float* x     = (const float*)d_in[0];
    const float* Wq    = (const float*)d_in[1];
    const float* Wk    = (const float*)d_in[2];
    const float* Wv    = (const float*)d_in[3];
    const float* Wg    = (const float*)d_in[4];
    const float* bg    = (const float*)d_in[5];
    const float* Wo    = (const float*)d_in[6];
    const float* mem_k = (const float*)d_in[7];
    const float* mem_v = (const float*)d_in[8];
    const float* freqs = (const float*)d_in[9];

    // Workspace (~28.8 MB). attnb aliases Xb (Xb dead after gemm_qkvg_mfma).
    unsigned short* q_b = (unsigned short*)d_ws;               // [H][N][64] bf16
    unsigned short* k_b = q_b + (size_t)NH * TN * DHD;         // [H][JPAD][64] bf16
    unsigned short* v_b = k_b + (size_t)NH * JPAD * DHD;       // [H][JPAD][64] bf16
    unsigned short* Xb  = v_b + (size_t)NH * JPAD * DHD;       // [N][512] bf16
    unsigned short* attnb = Xb;                                // alias
    unsigned short* Wt  = Xb + (size_t)TN * DM;                // 5x[512][512] bf16
    float* graw = (float*)(Wt + (size_t)5 * DM * DM);          // [N][512] fp32 gate
    float2* tab = (float2*)(graw + (size_t)TN * DM);           // [4096][64] cos/sin

    // 0) prep: cast X, transpose weights, rope table, memory KV rows
    prep<<<dim3(2440), 256, 0, stream>>>(x, Xb, Wq, Wk, Wv, Wg, Wo, Wt,
                                         freqs, tab, mem_k, mem_v, k_b, v_b);

    // 1) Q/K/V/G projections (bf16 MFMA) + fused l2norm/RoPE/gate epilogues
    gemm_qkvg_mfma<<<dim3(TN / 128, DM / 128, 4), 256, 0, stream>>>(
        Xb, Wt, tab, bg, q_b, k_b, v_b, graw);

    // 2) MFMA local-window attention (2 j-groups, fixed-max softmax)
    attn_mfma<<<dim3(512), 512, 0, stream>>>(q_b, k_b, v_b, graw, attnb);

    // 3) output projection (bf16 MFMA)
    gemm_out_mfma<<<dim3(TN / 128, DM / 128), 256, 0, stream>>>(
        attnb, Wt + (size_t)4 * DM * DM, (float*)d_out);
}

// Round 12
// 143.539 us; speedup vs baseline: 4.8370x; 1.0939x over previous
//
#include <hip/hip_runtime.h>
#include <math.h>

// Problem constants
#define TN 4096        // sequence length N
#define DM 512         // model dim D = H*DH
#define NH 8           // heads
#define DHD 64         // head dim
#define MEM 4          // memory slots M
#define WINR 512       // window radius
#define JTOT (TN + MEM)   // 4100 total keys
#define JPAD 4168      // padded key rows so tile over-reads stay in-bounds
#define QK_SCALE 10.0f

typedef __attribute__((ext_vector_type(8))) short bf16x8;   // 8 bf16 = 4 VGPRs (MFMA A/B frag)
typedef __attribute__((ext_vector_type(4))) float f32x4;    // MFMA C/D frag

// fp32 -> bf16 round-to-nearest-even
__device__ __forceinline__ unsigned short f2bf(float f) {
    unsigned u = __float_as_uint(f);
    u = (u + 0x7FFFu + ((u >> 16) & 1u)) >> 16;
    return (unsigned short)u;
}

// async global->LDS, 16B per lane (wave writes base + lane*16, linear).
// LDS dest expression must be wave-uniform (guide m104); global src per-lane.
__device__ __forceinline__ void gl_lds16(const unsigned short* g, unsigned short* l) {
    __builtin_amdgcn_global_load_lds(
        (const __attribute__((address_space(1))) unsigned int*)g,
        (__attribute__((address_space(3))) unsigned int*)l, 16, 0, 0);
}

// ---------------------------------------------------------------------------
// Sectioned prep kernel (one launch, 2440 blocks):
//   blocks    0..2047 : cast X fp32 -> bf16   (2048*256*4 = TN*DM)
//   blocks 2048..2367 : transpose+cast 5 weight matrices -> Wt (bf16, [n][k])
//   blocks 2368..2431 : rope table tab[n][d] = (cos,sin) fp32
//   blocks 2432..2439 : memory KV rows (l2norm mem_k, mem_v) as bf16
// ---------------------------------------------------------------------------
__global__ __launch_bounds__(256)
void prep(const float* __restrict__ X, unsigned short* __restrict__ Xb,
          const float* __restrict__ W0, const float* __restrict__ W1,
          const float* __restrict__ W2, const float* __restrict__ W3,
          const float* __restrict__ W4, unsigned short* __restrict__ T,
          const float* __restrict__ freqs, float2* __restrict__ tab,
          const float* __restrict__ mem_k, const float* __restrict__ mem_v,
          unsigned short* __restrict__ k_b, unsigned short* __restrict__ v_b)
{
    const int b = blockIdx.x;
    const int t = threadIdx.x;

    if (b < 2048) {                      // ---- cast X (full matrix)
        int idx = b * 256 + t;
        float4 v = *(const float4*)&X[(size_t)idx * 4];
        *(ushort4*)&Xb[(size_t)idx * 4] =
            make_ushort4(f2bf(v.x), f2bf(v.y), f2bf(v.z), f2bf(v.w));
    } else if (b < 2368) {               // ---- weight transpose+cast
        __shared__ unsigned short Ts[64][68];
        int bi = b - 2048;
        int sel = bi >> 6, tile = bi & 63;
        const float* __restrict__ W =
            (sel == 0) ? W0 : (sel == 1) ? W1 : (sel == 2) ? W2 : (sel == 3) ? W3 : W4;
        unsigned short* __restrict__ Wt = T + (size_t)sel * DM * DM;
        int r0 = (tile >> 3) * 64, c0 = (tile & 7) * 64;
        #pragma unroll
        for (int p = 0; p < 4; ++p) {
            int i  = p * 16 + (t >> 4);
            int j4 = (t & 15) * 4;
            float4 v = *(const float4*)&W[(size_t)(r0 + i) * DM + c0 + j4];
            Ts[i][j4 + 0] = f2bf(v.x); Ts[i][j4 + 1] = f2bf(v.y);
            Ts[i][j4 + 2] = f2bf(v.z); Ts[i][j4 + 3] = f2bf(v.w);
        }
        __syncthreads();
        #pragma unroll
        for (int p = 0; p < 4; ++p) {
            int oc  = p * 16 + (t >> 4);
            int or4 = (t & 15) * 4;
            *(ushort4*)&Wt[(size_t)(c0 + oc) * DM + r0 + or4] =
                make_ushort4(Ts[or4 + 0][oc], Ts[or4 + 1][oc],
                             Ts[or4 + 2][oc], Ts[or4 + 3][oc]);
        }
    } else if (b < 2432) {               // ---- rope cos/sin table
        int tid = (b - 2368) * 256 + t;
        #pragma unroll
        for (int e = 0; e < 16; ++e) {
            int id = e * 16384 + tid;
            float f = freqs[id];
            float sn, cs;
            sincosf(f, &sn, &cs);
            tab[id] = make_float2(cs, sn);
        }
    } else {                             // ---- memory KV rows
        int gw   = (b - 2432) * 4 + (t >> 6);
        int lane = t & 63;
        int h = gw >> 2, m = gw & 3;
        float kv = mem_k[(size_t)(h * MEM + m) * DHD + lane];
        float s = kv * kv;
        #pragma unroll
        for (int off = 1; off < 64; off <<= 1) s += __shfl_xor(s, off);
        kv = kv / fmaxf(sqrtf(s), 1e-12f);
        k_b[((size_t)h * JPAD + m) * 64 + lane] = f2bf(kv);
        v_b[((size_t)h * JPAD + m) * 64 + lane] =
            f2bf(mem_v[(size_t)(h * MEM + m) * DHD + lane]);
    }
}

// ---------------------------------------------------------------------------
// bf16 MFMA GEMM for Q/K/V/G projections, global_load_lds staging (width 16).
// LDS [128][32] LINEAR (required: DMA writes wave-uniform base + lane*16).
// Fused epilogues: q/k l2norm+RoPE->bf16; v bf16; g sigmoid->fp32.
// ---------------------------------------------------------------------------
__global__ __launch_bounds__(256)
void gemm_qkvg_mfma(const unsigned short* __restrict__ Xb,
                    const unsigned short* __restrict__ Wt,
                    const float2* __restrict__ tab,
                    const float* __restrict__ bg,
                    unsigned short* __restrict__ q_b,
                    unsigned short* __restrict__ k_b,
                    unsigned short* __restrict__ v_b,
                    float* __restrict__ graw)
{
    __shared__ __align__(16) unsigned short As[128][32];
    __shared__ __align__(16) unsigned short Bs[128][32];
    const int sel = blockIdx.z;
    const unsigned short* __restrict__ Wsel = Wt + (size_t)sel * DM * DM;
    const int row0 = blockIdx.x * 128;
    const int col0 = blockIdx.y * 128;
    const int t = threadIdx.x;
    const int w = t >> 6, l = t & 63;
    const int wm = w >> 1, wn = w & 1;
    const int l15 = l & 15, lh = l >> 4;
    const int wb = t & 192;              // wave-uniform (w*64)

    f32x4 acc[4][4];
    #pragma unroll
    for (int mi = 0; mi < 4; ++mi)
        #pragma unroll
        for (int ni = 0; ni < 4; ++ni)
            acc[mi][ni] = (f32x4){0.f, 0.f, 0.f, 0.f};

    for (int k0 = 0; k0 < DM; k0 += 32) {
        __syncthreads();   // previous tile's readers done
        #pragma unroll
        for (int cc = 0; cc < 2; ++cc) {
            int c = t + cc * 256;          // per-lane load index 0..511
            int row = c >> 2, k8 = c & 3;
            gl_lds16(&Xb[(size_t)(row0 + row) * DM + k0 + k8 * 8],
                     &As[0][0] + (size_t)(wb + cc * 256) * 8);
            gl_lds16(&Wsel[(size_t)(col0 + row) * DM + k0 + k8 * 8],
                     &Bs[0][0] + (size_t)(wb + cc * 256) * 8);
        }
        __syncthreads();   // drains vmcnt before barrier (compiler-inserted)

        bf16x8 af[4], bfr[4];
        #pragma unroll
        for (int mi = 0; mi < 4; ++mi)
            af[mi] = *(const bf16x8*)&As[wm * 64 + mi * 16 + l15][lh * 8];
        #pragma unroll
        for (int ni = 0; ni < 4; ++ni)
            bfr[ni] = *(const bf16x8*)&Bs[wn * 64 + ni * 16 + l15][lh * 8];
        #pragma unroll
        for (int mi = 0; mi < 4; ++mi)
            #pragma unroll
            for (int ni = 0; ni < 4; ++ni)
                acc[mi][ni] = __builtin_amdgcn_mfma_f32_16x16x32_bf16(
                    af[mi], bfr[ni], acc[mi][ni], 0, 0, 0);
    }

    if (sel <= 1) {
        const int h = (col0 + wn * 64) >> 6;
        #pragma unroll
        for (int mi = 0; mi < 4; ++mi) {
            #pragma unroll
            for (int r = 0; r < 4; ++r) {
                float v0 = acc[mi][0][r], v1 = acc[mi][1][r];
                float v2 = acc[mi][2][r], v3 = acc[mi][3][r];
                float ss = v0 * v0 + v1 * v1 + v2 * v2 + v3 * v3;
                ss += __shfl_xor(ss, 1); ss += __shfl_xor(ss, 2);
                ss += __shfl_xor(ss, 4); ss += __shfl_xor(ss, 8);
                float inv = 1.0f / fmaxf(sqrtf(ss), 1e-12f);
                v0 *= inv; v1 *= inv; v2 *= inv; v3 *= inv;
                int n = row0 + wm * 64 + mi * 16 + lh * 4 + r;
                float2 t0 = tab[n * 64 + l15];
                float2 t1 = tab[n * 64 + 16 + l15];
                float o0 = v0 * t0.x - v2 * t0.y;
                float o1 = v1 * t1.x - v3 * t1.y;
                float o2 = v2 * t0.x + v0 * t0.y;
                float o3 = v3 * t1.x + v1 * t1.y;
                unsigned short* dst = (sel == 0)
                    ? &q_b[((size_t)h * TN + n) * 64]
                    : &k_b[((size_t)h * JPAD + MEM + n) * 64];
                dst[l15]      = f2bf(o0);
                dst[16 + l15] = f2bf(o1);
                dst[32 + l15] = f2bf(o2);
                dst[48 + l15] = f2bf(o3);
            }
        }
    } else if (sel == 2) {
        const int h = (col0 + wn * 64) >> 6;
        #pragma unroll
        for (int mi = 0; mi < 4; ++mi)
            #pragma unroll
            for (int ni = 0; ni < 4; ++ni) {
                int d = ni * 16 + l15;
                #pragma unroll
                for (int r = 0; r < 4; ++r) {
                    int grow = row0 + wm * 64 + mi * 16 + lh * 4 + r;
                    v_b[((size_t)h * JPAD + MEM + grow) * 64 + d] = f2bf(acc[mi][ni][r]);
                }
            }
    } else {
        #pragma unroll
        for (int mi = 0; mi < 4; ++mi)
            #pragma unroll
            for (int ni = 0; ni < 4; ++ni) {
                int gcol = col0 + wn * 64 + ni * 16 + l15;
                float bgv = bg[gcol];
                #pragma unroll
                for (int r = 0; r < 4; ++r) {
                    int grow = row0 + wm * 64 + mi * 16 + lh * 4 + r;
                    float g = acc[mi][ni][r] + bgv;
                    graw[(size_t)grow * DM + gcol] = 1.0f / (1.0f + __expf(-g));
                }
            }
    }
}

// ---------------------------------------------------------------------------
// bf16 MFMA GEMM: d_out = attnb @ Wo, global_load_lds staging.
// ---------------------------------------------------------------------------
__global__ __launch_bounds__(256)
void gemm_out_mfma(const unsigned short* __restrict__ Ab,
                   const unsigned short* __restrict__ Wot,
                   float* __restrict__ C)
{
    __shared__ __align__(16) unsigned short As[128][32];
    __shared__ __align__(16) unsigned short Bs[128][32];
    const int row0 = blockIdx.x * 128;
    const int col0 = blockIdx.y * 128;
    const int t = threadIdx.x;
    const int w = t >> 6, l = t & 63;
    const int wm = w >> 1, wn = w & 1;
    const int wb = t & 192;

    f32x4 acc[4][4];
    #pragma unroll
    for (int mi = 0; mi < 4; ++mi)
        #pragma unroll
        for (int ni = 0; ni < 4; ++ni)
            acc[mi][ni] = (f32x4){0.f, 0.f, 0.f, 0.f};

    for (int k0 = 0; k0 < DM; k0 += 32) {
        __syncthreads();
        #pragma unroll
        for (int cc = 0; cc < 2; ++cc) {
            int c = t + cc * 256;
            int row = c >> 2, k8 = c & 3;
            gl_lds16(&Ab[(size_t)(row0 + row) * DM + k0 + k8 * 8],
                     &As[0][0] + (size_t)(wb + cc * 256) * 8);
            gl_lds16(&Wot[(size_t)(col0 + row) * DM + k0 + k8 * 8],
                     &Bs[0][0] + (size_t)(wb + cc * 256) * 8);
        }
        __syncthreads();

        bf16x8 af[4], bfr[4];
        #pragma unroll
        for (int mi = 0; mi < 4; ++mi)
            af[mi] = *(const bf16x8*)&As[wm * 64 + mi * 16 + (l & 15)][(l >> 4) * 8];
        #pragma unroll
        for (int ni = 0; ni < 4; ++ni)
            bfr[ni] = *(const bf16x8*)&Bs[wn * 64 + ni * 16 + (l & 15)][(l >> 4) * 8];
        #pragma unroll
        for (int mi = 0; mi < 4; ++mi)
            #pragma unroll
            for (int ni = 0; ni < 4; ++ni)
                acc[mi][ni] = __builtin_amdgcn_mfma_f32_16x16x32_bf16(
                    af[mi], bfr[ni], acc[mi][ni], 0, 0, 0);
    }

    #pragma unroll
    for (int mi = 0; mi < 4; ++mi)
        #pragma unroll
        for (int ni = 0; ni < 4; ++ni) {
            int gcol = col0 + wn * 64 + ni * 16 + (l & 15);
            #pragma unroll
            for (int r = 0; r < 4; ++r) {
                int grow = row0 + wm * 64 + mi * 16 + (l >> 4) * 4 + r;
                C[(size_t)grow * DM + gcol] = acc[mi][ni][r];
            }
        }
}

// ---------------------------------------------------------------------------
// MFMA flash attention, 512 threads = 2 independent j-groups of 4 waves.
// Fixed-max softmax; mask computation HOISTED: fully-interior tiles (15/17)
// take a no-mask fast path (wave-uniform branch).
// ---------------------------------------------------------------------------
#define TILE_US (64 * 72)
__global__ __launch_bounds__(512)
void attn_mfma(const unsigned short* __restrict__ qb,
               const unsigned short* __restrict__ kb,
               const unsigned short* __restrict__ vb,
               const float* __restrict__ gate,
               unsigned short* __restrict__ attnb)
{
    __shared__ __align__(16) unsigned short smem[TILE_US * 7];
    unsigned short* Qs = smem;
    #define KS(g) (smem + TILE_US * (1 + (g)))
    #define VT(g) (smem + TILE_US * (3 + (g)))
    #define PS(g) (smem + TILE_US * (5 + (g)))

    const int sw   = (blockIdx.x & 7) * 64 + (blockIdx.x >> 3);
    const int head = sw >> 6;
    const int n0   = (sw & 63) * 64;
    const int t   = threadIdx.x;
    const int g   = t >> 8;
    const int tig = t & 255;
    const int wid = (t >> 6) & 3;
    const int l   = t & 63;
    const int l15 = l & 15, lh = l >> 4;

    {
        int row = t >> 3, c8 = (t & 7) * 8;
        *(bf16x8*)&Qs[row * 72 + c8] =
            *(const bf16x8*)&qb[((size_t)(head * TN + n0 + row)) * 64 + c8];
    }

    f32x4 oacc[4];
    #pragma unroll
    for (int dt = 0; dt < 4; ++dt) oacc[dt] = (f32x4){0.f, 0.f, 0.f, 0.f};
    float lpart[4] = {0.f, 0.f, 0.f, 0.f};

    const int p_base = MEM + n0;
    const int kstart = max(0, p_base - WINR);
    const int kend   = min(JTOT, p_base + 63 + WINR + 1);
    const int ntiles = (kend - kstart + 63) >> 6;
    const int niter  = (ntiles + 1) >> 1;

    const int srow = tig >> 3, sc8 = (tig & 7) * 8;
    const int srow2 = (tig + 256) >> 3, sc82 = ((tig + 256) & 7) * 8;
    const int vj = tig & 63, vd0 = (tig >> 6) * 8;
    const int vj2 = (tig + 256) & 63, vd02 = ((tig + 256) >> 6) * 8;
    bf16x8 kr0, kr1, vr0, vr1;

    int tj = g;
    {
        int j0 = kstart + tj * 64;
        kr0 = *(const bf16x8*)&kb[((size_t)head * JPAD + j0 + srow) * 64 + sc8];
        kr1 = *(const bf16x8*)&kb[((size_t)head * JPAD + j0 + srow2) * 64 + sc82];
        vr0 = *(const bf16x8*)&vb[((size_t)head * JPAD + j0 + vj) * 64 + vd0];
        vr1 = *(const bf16x8*)&vb[((size_t)head * JPAD + j0 + vj2) * 64 + vd02];
    }

    for (int it = 0; it < niter; ++it) {
        bool valid = (tj < ntiles);
        __syncthreads();
        if (valid) {
            *(bf16x8*)&KS(g)[srow * 72 + sc8]   = kr0;
            *(bf16x8*)&KS(g)[srow2 * 72 + sc82] = kr1;
            #pragma unroll
            for (int i = 0; i < 8; ++i) VT(g)[(vd0 + i) * 72 + vj]   = (unsigned short)vr0[i];
            #pragma unroll
            for (int i = 0; i < 8; ++i) VT(g)[(vd02 + i) * 72 + vj2] = (unsigned short)vr1[i];
        }
        __syncthreads();

        if (valid) {
            int j0 = kstart + tj * 64;
            if (tj + 2 < ntiles) {
                int jn = kstart + (tj + 2) * 64;
                kr0 = *(const bf16x8*)&kb[((size_t)head * JPAD + jn + srow) * 64 + sc8];
                kr1 = *(const bf16x8*)&kb[((size_t)head * JPAD + jn + srow2) * 64 + sc82];
                vr0 = *(const bf16x8*)&vb[((size_t)head * JPAD + jn + vj) * 64 + vd0];
                vr1 = *(const bf16x8*)&vb[((size_t)head * JPAD + jn + vj2) * 64 + vd02];
            }

            // S band = Q[band] @ K^T
            f32x4 sacc[4];
            #pragma unroll
            for (int kt = 0; kt < 4; ++kt) sacc[kt] = (f32x4){0.f, 0.f, 0.f, 0.f};
            __builtin_amdgcn_s_setprio(1);
            #pragma unroll
            for (int s = 0; s < 2; ++s) {
                bf16x8 a = *(const bf16x8*)&Qs[(wid * 16 + l15) * 72 + s * 32 + lh * 8];
                #pragma unroll
                for (int kt = 0; kt < 4; ++kt) {
                    bf16x8 b = *(const bf16x8*)&KS(g)[(kt * 16 + l15) * 72 + s * 32 + lh * 8];
                    sacc[kt] = __builtin_amdgcn_mfma_f32_16x16x32_bf16(a, b, sacc[kt], 0, 0, 0);
                }
            }
            __builtin_amdgcn_s_setprio(0);

            // fixed-max softmax: P = exp(10*s - 10). Wave-uniform mask hoist:
            // band q-range [p_base+wid*16, +15]; tile j-range [j0, j0+63].
            int qlo = p_base + wid * 16;
            bool fullok = ((qlo + 15 - j0) <= WINR) &&
                          ((qlo - (j0 + 63)) >= -WINR) &&
                          (j0 + 63 < JTOT);
            if (fullok) {
                #pragma unroll
                for (int r = 0; r < 4; ++r) {
                    #pragma unroll
                    for (int kt = 0; kt < 4; ++kt) {
                        float pe = __expf(sacc[kt][r] * QK_SCALE - 10.0f);
                        lpart[r] += pe;
                        PS(g)[(wid * 16 + lh * 4 + r) * 72 + kt * 16 + l15] = f2bf(pe);
                    }
                }
            } else {
                #pragma unroll
                for (int r = 0; r < 4; ++r) {
                    int pq = p_base + wid * 16 + lh * 4 + r;
                    #pragma unroll
                    for (int kt = 0; kt < 4; ++kt) {
                        int j = j0 + kt * 16 + l15;
                        int dist = pq - j;
                        bool ok = (dist <= WINR) && (dist >= -WINR) && (j < JTOT);
                        float pe = ok ? __expf(sacc[kt][r] * QK_SCALE - 10.0f) : 0.f;
                        lpart[r] += pe;
                        PS(g)[(wid * 16 + lh * 4 + r) * 72 + kt * 16 + l15] = f2bf(pe);
                    }
                }
            }

            // O += P @ V
            __builtin_amdgcn_s_setprio(1);
            #pragma unroll
            for (int s = 0; s < 2; ++s) {
                bf16x8 a = *(const bf16x8*)&PS(g)[(wid * 16 + l15) * 72 + s * 32 + lh * 8];
                #pragma unroll
                for (int dt = 0; dt < 4; ++dt) {
                    bf16x8 b = *(const bf16x8*)&VT(g)[(dt * 16 + l15) * 72 + s * 32 + lh * 8];
                    oacc[dt] = __builtin_amdgcn_mfma_f32_16x16x32_bf16(a, b, oacc[dt], 0, 0, 0);
                }
            }
            __builtin_amdgcn_s_setprio(0);
        }
        tj += 2;
    }

    // ---- combine group partials (fbuf aliases smem; all tiles dead) ----
    float* fbuf = (float*)smem;
    __syncthreads();
    if (g == 1) {
        #pragma unroll
        for (int dt = 0; dt < 4; ++dt)
            #pragma unroll
            for (int r = 0; r < 4; ++r)
                fbuf[tig * 21 + dt * 4 + r] = oacc[dt][r];
        #pragma unroll
        for (int r = 0; r < 4; ++r) fbuf[tig * 21 + 16 + r] = lpart[r];
    }
    __syncthreads();
    if (g == 0) {
        #pragma unroll
        for (int dt = 0; dt < 4; ++dt)
            #pragma unroll
            for (int r = 0; r < 4; ++r)
                oacc[dt][r] += fbuf[tig * 21 + dt * 4 + r];
        #pragma unroll
        for (int r = 0; r < 4; ++r) lpart[r] += fbuf[tig * 21 + 16 + r];

        #pragma unroll
        for (int r = 0; r < 4; ++r) {
            float rs = lpart[r];
            rs += __shfl_xor(rs, 1); rs += __shfl_xor(rs, 2);
            rs += __shfl_xor(rs, 4); rs += __shfl_xor(rs, 8);
            float inv = 1.0f / rs;
            int n = n0 + wid * 16 + lh * 4 + r;
            #pragma unroll
            for (int dt = 0; dt < 4; ++dt) {
                int col = head * 64 + dt * 16 + l15;
                float gv = gate[(size_t)n * DM + col];
                attnb[(size_t)n * DM + col] = f2bf(oacc[dt][r] * inv * gv);
            }
        }
    }
}

// ---------------------------------------------------------------------------
extern "C" void kernel_launch(void* const* d_in, const int* in_sizes, int n_in,
                              void* d_out, int out_size, void* d_ws, size_t ws_size,
                              hipStream_t stream)
{
    const float* x     = (const float*)d_in[0];
    const float* Wq    = (const float*)d_in[1];
    const float* Wk    = (const float*)d_in[2];
    const float* Wv    = (const float*)d_in[3];
    const float* Wg    = (const float*)d_in[4];
    const float* bg    = (const float*)d_in[5];
    const float* Wo    = (const float*)d_in[6];
    const float* mem_k = (const float*)d_in[7];
    const float* mem_v = (const float*)d_in[8];
    const float* freqs = (const float*)d_in[9];

    // Workspace (~28.8 MB). attnb aliases Xb (Xb dead after gemm_qkvg_mfma).
    unsigned short* q_b = (unsigned short*)d_ws;               // [H][N][64] bf16
    unsigned short* k_b = q_b + (size_t)NH * TN * DHD;         // [H][JPAD][64] bf16
    unsigned short* v_b = k_b + (size_t)NH * JPAD * DHD;       // [H][JPAD][64] bf16
    unsigned short* Xb  = v_b + (size_t)NH * JPAD * DHD;       // [N][512] bf16
    unsigned short* attnb = Xb;                                // alias
    unsigned short* Wt  = Xb + (size_t)TN * DM;                // 5x[512][512] bf16
    float* graw = (float*)(Wt + (size_t)5 * DM * DM);          // [N][512] fp32 gate
    float2* tab = (float2*)(graw + (size_t)TN * DM);           // [4096][64] cos/sin

    // 0) prep: cast X, transpose weights, rope table, memory KV rows
    prep<<<dim3(2440), 256, 0, stream>>>(x, Xb, Wq, Wk, Wv, Wg, Wo, Wt,
                                         freqs, tab, mem_k, mem_v, k_b, v_b);

    // 1) Q/K/V/G projections (bf16 MFMA, global_load_lds) + fused epilogues
    gemm_qkvg_mfma<<<dim3(TN / 128, DM / 128, 4), 256, 0, stream>>>(
        Xb, Wt, tab, bg, q_b, k_b, v_b, graw);

    // 2) MFMA local-window attention (2 j-groups, fixed-max softmax, mask hoist)
    attn_mfma<<<dim3(512), 512, 0, stream>>>(q_b, k_b, v_b, graw, attnb);

    // 3) output projection (bf16 MFMA, global_load_lds)
    gemm_out_mfma<<<dim3(TN / 128, DM / 128), 256, 0, stream>>>(
        attnb, Wt + (size_t)4 * DM * DM, (float*)d_out);
}